// Round 2
// baseline (967.652 us; speedup 1.0000x reference)
//
#include <hip/hip_runtime.h>
#include <math.h>

#define B_ 32
#define T_ 1000
#define M_ 32000   // B_*T_

// ---------------- workspace layout (float offsets) ----------------
constexpr size_t OFF_M     = 0;                       // 64*44
constexpr size_t OFF_B2    = 2816;                    // 64
constexpr size_t OFF_WEFF  = 2880;                    // 160*128
constexpr size_t OFF_BEFF  = 23360;                   // 160
constexpr size_t OFF_A2    = 23520;                   // 128*16
constexpr size_t OFF_WCLS  = 25568;                   // 4*4096
constexpr size_t OFF_X2    = 41952;                   // 32000*64   (also y2 after K6)
constexpr size_t OFF_XZ    = OFF_X2    + 2048000;     // 32000*256  (xs half -> du after K4; z half)
constexpr size_t OFF_U     = OFF_XZ    + 8192000;     // 32000*128
constexpr size_t OFF_DELTA = OFF_U     + 4096000;     // 32000*128  (scan overwrites with y in-place)
constexpr size_t OFF_BM    = OFF_DELTA + 4096000;     // 32000*16
constexpr size_t OFF_CM    = OFF_BM    + 512000;      // 32000*16
constexpr size_t WS_FLOATS = OFF_CM    + 512000;      // 19,497,952 floats ≈ 78 MB

__device__ __forceinline__ float sigm_(float x)  { return 1.f / (1.f + __expf(-x)); }
__device__ __forceinline__ float silu_(float x)  { return x * sigm_(x); }
__device__ __forceinline__ float softp_(float x) { return fmaxf(x, 0.f) + log1pf(__expf(-fabsf(x))); }

// ---------------- K0: fold all small params ----------------
__global__ __launch_bounds__(256) void k0_prep(
    const float* __restrict__ sconv_w, const float* __restrict__ bn1_g, const float* __restrict__ bn1_b,
    const float* __restrict__ bn1_m, const float* __restrict__ bn1_v,
    const float* __restrict__ enc_w, const float* __restrict__ enc_b,
    const float* __restrict__ bn2_g, const float* __restrict__ bn2_b,
    const float* __restrict__ bn2_m, const float* __restrict__ bn2_v,
    const float* __restrict__ xpw, const float* __restrict__ dtw, const float* __restrict__ dtb,
    const float* __restrict__ A_log, const float* __restrict__ cls_w,
    float* __restrict__ Mmat, float* __restrict__ bias2, float* __restrict__ Weff,
    float* __restrict__ beff, float* __restrict__ A2, float* __restrict__ wcls)
{
    __shared__ float s1[128], b1[128], s2[64], b2f[64];
    const int idx = threadIdx.x;
    if (idx < 128) {
        float s = bn1_g[idx] * rsqrtf(bn1_v[idx] + 1e-5f);
        s1[idx] = s; b1[idx] = bn1_b[idx] - bn1_m[idx] * s;
    }
    if (idx < 64) {
        float s = bn2_g[idx] * rsqrtf(bn2_v[idx] + 1e-5f);
        s2[idx] = s; b2f[idx] = bn2_b[idx] - bn2_m[idx] * s;
    }
    __syncthreads();

    // folded frontend matrix M[o][j], j in [0,44): group g=j/22, tap i=j%22
    for (int e = idx; e < 64 * 44; e += 256) {
        int o = e / 44, j = e % 44, g = j / 22, i = j % 22;
        float acc = 0.f;
        for (int cc = 0; cc < 64; ++cc) {
            int c = g * 64 + cc;
            float ew = enc_w[(o * 64 + cc) * 2 + g];
            acc += ew * s1[c] * sconv_w[c * 22 + i];
        }
        Mmat[e] = acc * s2[o];
    }
    if (idx < 64) {
        int o = idx; float acc = 0.f;
        for (int c = 0; c < 128; ++c) {
            int g = c >> 6, i = c & 63;
            acc += enc_w[(o * 64 + i) * 2 + g] * b1[c];
        }
        bias2[o] = s2[o] * (acc + enc_b[o]) + b2f[o];
    }
    // Weff rows 0..127 = dt_proj_w @ x_proj_w[0:4]
    for (int e = idx; e < 128 * 128; e += 256) {
        int d = e >> 7, k = e & 127;
        float acc = 0.f;
        #pragma unroll
        for (int r = 0; r < 4; ++r) acc += dtw[d * 4 + r] * xpw[r * 128 + k];
        Weff[e] = acc;
    }
    // rows 128..159 = x_proj rows 4..35 (B then C)
    for (int e = idx; e < 32 * 128; e += 256) {
        int q = e >> 7, k = e & 127;
        Weff[128 * 128 + e] = xpw[(4 + q) * 128 + k];
    }
    if (idx < 160) beff[idx] = (idx < 128) ? dtb[idx] : 0.f;

    const float LOG2E = 1.4426950408889634f;
    for (int e = idx; e < 2048; e += 256) A2[e] = -expf(A_log[e]) * LOG2E;

    // normalized classifier weights
    int wid = idx >> 6, lane = idx & 63;
    for (int c = wid; c < 4; c += 4) {
        float p = 0.f;
        for (int f = lane; f < 4096; f += 64) { float v = cls_w[c * 4096 + f]; p += v * v; }
        #pragma unroll
        for (int off = 32; off; off >>= 1) p += __shfl_xor(p, off);
        float sc = fminf(1.f, 0.5f / (sqrtf(p) + 1e-7f));
        for (int f = lane; f < 4096; f += 64) wcls[c * 4096 + f] = cls_w[c * 4096 + f] * sc;
    }
}

// ---------------- K1: folded frontend GEMM 44 -> 64 ----------------
__global__ __launch_bounds__(256) void k1_frontend(
    const float* __restrict__ x, const float* __restrict__ Mmat,
    const float* __restrict__ bias2, float* __restrict__ x2)
{
    __shared__ float Ml[64 * 44];
    __shared__ float xl[44][32];
    const int b = blockIdx.x >> 5, tile = blockIdx.x & 31;
    const int t0 = tile * 32;
    const int idx = threadIdx.x;
    for (int e = idx; e < 64 * 44; e += 256) Ml[e] = Mmat[e];
    {
        int i = idx & 31, j0 = idx >> 5;
        for (int j = j0; j < 44; j += 8) {
            int t = t0 + i;
            xl[j][i] = (t < T_) ? x[(b * 44 + j) * T_ + t] : 0.f;
        }
    }
    __syncthreads();
    const int tl = idx & 31, os = idx >> 5;
    const int t = t0 + tl;
    if (t >= T_) return;
    float acc[8];
    #pragma unroll
    for (int q = 0; q < 8; ++q) acc[q] = bias2[os * 8 + q];
    for (int j = 0; j < 44; ++j) {
        float xv = xl[j][tl];
        #pragma unroll
        for (int q = 0; q < 8; ++q) acc[q] = fmaf(Ml[(os * 8 + q) * 44 + j], xv, acc[q]);
    }
    float4* dst = (float4*)&x2[((size_t)(b * T_ + t)) * 64 + os * 8];
    dst[0] = make_float4(acc[0], acc[1], acc[2], acc[3]);
    dst[1] = make_float4(acc[4], acc[5], acc[6], acc[7]);
}

// ---------------- K2: in_proj GEMM 64 -> 256 ----------------
__global__ __launch_bounds__(256) void k2_inproj(
    const float* __restrict__ x2, const float* __restrict__ W, float* __restrict__ xz)
{
    __shared__ float al[64 * 68];
    __shared__ float bl[64 * 68];
    const int mt = blockIdx.x >> 2, nt = blockIdx.x & 3;
    const int m0 = mt * 64, n0 = nt * 64;
    const int idx = threadIdx.x;
    {
        int mp = idx >> 2, kq = idx & 3;
        #pragma unroll
        for (int f = 0; f < 4; ++f) {
            int k = kq * 16 + f * 4;
            float4 v = *(const float4*)&x2[(size_t)(m0 + mp) * 64 + k];
            al[(k + 0) * 68 + mp] = v.x; al[(k + 1) * 68 + mp] = v.y;
            al[(k + 2) * 68 + mp] = v.z; al[(k + 3) * 68 + mp] = v.w;
            float4 w = *(const float4*)&W[(size_t)(n0 + mp) * 64 + k];
            bl[(k + 0) * 68 + mp] = w.x; bl[(k + 1) * 68 + mp] = w.y;
            bl[(k + 2) * 68 + mp] = w.z; bl[(k + 3) * 68 + mp] = w.w;
        }
    }
    __syncthreads();
    const int ti = idx >> 4, ni = idx & 15;
    float acc[4][4] = {};
    for (int k = 0; k < 64; ++k) {
        float4 a = *(const float4*)&al[k * 68 + ti * 4];
        float4 w = *(const float4*)&bl[k * 68 + ni * 4];
        float av[4] = {a.x, a.y, a.z, a.w};
        float wv[4] = {w.x, w.y, w.z, w.w};
        #pragma unroll
        for (int r = 0; r < 4; ++r)
            #pragma unroll
            for (int c = 0; c < 4; ++c) acc[r][c] = fmaf(av[r], wv[c], acc[r][c]);
    }
    #pragma unroll
    for (int r = 0; r < 4; ++r)
        *(float4*)&xz[(size_t)(m0 + ti * 4 + r) * 256 + n0 + ni * 4] =
            make_float4(acc[r][0], acc[r][1], acc[r][2], acc[r][3]);
}

// ---------------- K3: depthwise conv1d(3) + silu -> u ----------------
__global__ __launch_bounds__(256) void k3_conv(
    const float* __restrict__ xz, const float* __restrict__ cw,
    const float* __restrict__ cb, float* __restrict__ u)
{
    const int gid = blockIdx.x * 256 + threadIdx.x;   // 32000*32
    const int m = gid >> 5, d4 = gid & 31;
    const int t = m % T_;
    const int d0 = d4 * 4;
    float4 z4 = make_float4(0.f, 0.f, 0.f, 0.f);
    float4 vm = (t > 0)      ? *(const float4*)&xz[(size_t)(m - 1) * 256 + d0] : z4;
    float4 v0 =                *(const float4*)&xz[(size_t)(m)     * 256 + d0];
    float4 vp = (t < T_ - 1) ? *(const float4*)&xz[(size_t)(m + 1) * 256 + d0] : z4;
    const float* pm = (const float*)&vm;
    const float* p0 = (const float*)&v0;
    const float* pp = (const float*)&vp;
    float r[4];
    #pragma unroll
    for (int e = 0; e < 4; ++e) {
        int d = d0 + e;
        float a = pm[e] * cw[d * 3 + 0] + p0[e] * cw[d * 3 + 1] + pp[e] * cw[d * 3 + 2] + cb[d];
        r[e] = silu_(a);
    }
    *(float4*)&u[(size_t)m * 128 + d0] = make_float4(r[0], r[1], r[2], r[3]);
}

// ---------------- K4: fused x_proj+dt GEMM 128 -> 160 (+softplus, du, B, C) ----------------
__global__ __launch_bounds__(256) void k4_xproj(
    const float* __restrict__ u, const float* __restrict__ Weff, const float* __restrict__ beff,
    float* __restrict__ delta, float* __restrict__ xz /* du dest, stride 256 */,
    float* __restrict__ Bm, float* __restrict__ Cm)
{
    __shared__ float al[64 * 68];
    __shared__ float bl[64 * 68];
    const int mt = blockIdx.x / 3, nt = blockIdx.x % 3;
    const int m0 = mt * 64, n0 = nt * 64;
    const int idx = threadIdx.x;
    const int ti = idx >> 4, ni = idx & 15;
    float acc[4][4] = {};
    for (int kb = 0; kb < 128; kb += 64) {
        __syncthreads();
        {
            int mp = idx >> 2, kq = idx & 3;
            #pragma unroll
            for (int f = 0; f < 4; ++f) {
                int k = kq * 16 + f * 4;
                float4 v = *(const float4*)&u[(size_t)(m0 + mp) * 128 + kb + k];
                al[(k + 0) * 68 + mp] = v.x; al[(k + 1) * 68 + mp] = v.y;
                al[(k + 2) * 68 + mp] = v.z; al[(k + 3) * 68 + mp] = v.w;
                int row = n0 + mp;
                float4 w = (row < 160) ? *(const float4*)&Weff[(size_t)row * 128 + kb + k]
                                       : make_float4(0.f, 0.f, 0.f, 0.f);
                bl[(k + 0) * 68 + mp] = w.x; bl[(k + 1) * 68 + mp] = w.y;
                bl[(k + 2) * 68 + mp] = w.z; bl[(k + 3) * 68 + mp] = w.w;
            }
        }
        __syncthreads();
        for (int k = 0; k < 64; ++k) {
            float4 a = *(const float4*)&al[k * 68 + ti * 4];
            float4 w = *(const float4*)&bl[k * 68 + ni * 4];
            float av[4] = {a.x, a.y, a.z, a.w};
            float wv[4] = {w.x, w.y, w.z, w.w};
            #pragma unroll
            for (int r = 0; r < 4; ++r)
                #pragma unroll
                for (int c = 0; c < 4; ++c) acc[r][c] = fmaf(av[r], wv[c], acc[r][c]);
        }
    }
    if (nt < 2) {
        #pragma unroll
        for (int r = 0; r < 4; ++r) {
            int m = m0 + ti * 4 + r;
            float4 uv = *(const float4*)&u[(size_t)m * 128 + n0 + ni * 4];
            const float* up = (const float*)&uv;
            float dl[4];
            #pragma unroll
            for (int c = 0; c < 4; ++c) {
                int n = n0 + ni * 4 + c;
                dl[c] = softp_(acc[r][c] + beff[n]);
            }
            *(float4*)&delta[(size_t)m * 128 + n0 + ni * 4] = make_float4(dl[0], dl[1], dl[2], dl[3]);
            *(float4*)&xz[(size_t)m * 256 + n0 + ni * 4] =
                make_float4(dl[0] * up[0], dl[1] * up[1], dl[2] * up[2], dl[3] * up[3]);
        }
    } else if (ni < 8) {
        float* dst = (ni < 4) ? Bm : Cm;
        int q0 = (ni & 3) * 4;
        #pragma unroll
        for (int r = 0; r < 4; ++r) {
            int m = m0 + ti * 4 + r;
            #pragma unroll
            for (int c = 0; c < 4; ++c) dst[(size_t)m * 16 + q0 + c] = acc[r][c];
        }
    }
}

// ---------------- K5: selective scan (writes y in-place over delta) ----------------
__global__ __launch_bounds__(256) void k5_scan(
    float* dy /* delta in, y out, stride 128 — NOT restrict (aliased) */,
    const float* __restrict__ du /* stride 256 */,
    const float* __restrict__ u, const float* __restrict__ Bm, const float* __restrict__ Cm,
    const float* __restrict__ A2, const float* __restrict__ Dp)
{
    const int tid = blockIdx.x * 256 + threadIdx.x;
    const int b = tid >> 11;
    const int r = tid & 2047;
    const int d = r >> 4, n = r & 15;
    const float a2 = A2[d * 16 + n];
    const float dpv = Dp[d];
    const bool wr = (n == 0);
    float h = 0.f;
    float*       dptr  = dy + (size_t)b * T_ * 128 + d;
    const float* duptr = du + (size_t)b * T_ * 256 + d;
    const float* uptr  = u  + (size_t)b * T_ * 128 + d;
    const float* bptr  = Bm + (size_t)b * T_ * 16  + n;
    const float* cptr  = Cm + (size_t)b * T_ * 16  + n;
    #pragma unroll 4
    for (int t = 0; t < T_; ++t) {
        float dl  = dptr[(size_t)t * 128];
        float duv = duptr[(size_t)t * 256];
        float bc  = bptr[(size_t)t * 16];
        float cc  = cptr[(size_t)t * 16];
        float dA  = exp2f(dl * a2);
        h = fmaf(dA, h, duv * bc);
        float p = h * cc;
        p += __shfl_xor(p, 1);
        p += __shfl_xor(p, 2);
        p += __shfl_xor(p, 4);
        p += __shfl_xor(p, 8);
        if (wr) dptr[(size_t)t * 128] = fmaf(uptr[(size_t)t * 128], dpv, p);
    }
}

// ---------------- K6: LayerNorm + silu(z) gate + out_proj 128 -> 64 ----------------
__global__ __launch_bounds__(256) void k6_out(
    const float* __restrict__ ys, const float* __restrict__ xz,
    const float* __restrict__ lng, const float* __restrict__ lnb,
    const float* __restrict__ Wout, float* __restrict__ y2)
{
    __shared__ float wt[128 * 65];
    __shared__ float yy[4][128];
    const int idx = threadIdx.x;
    for (int f = idx; f < 64 * 128; f += 256) {
        int o = f >> 7, d = f & 127;
        wt[d * 65 + o] = Wout[f];
    }
    const int wid = idx >> 6, lane = idx & 63;
    const int m = blockIdx.x * 4 + wid;
    float2 v = *(const float2*)&ys[(size_t)m * 128 + lane * 2];
    float s = v.x + v.y;
    float sq = v.x * v.x + v.y * v.y;
    #pragma unroll
    for (int off = 32; off; off >>= 1) { s += __shfl_xor(s, off); sq += __shfl_xor(sq, off); }
    float mu = s * (1.f / 128.f);
    float var = sq * (1.f / 128.f) - mu * mu;
    float rstd = rsqrtf(var + 1e-5f);
    float2 g  = *(const float2*)&lng[lane * 2];
    float2 be = *(const float2*)&lnb[lane * 2];
    float2 z  = *(const float2*)&xz[(size_t)m * 256 + 128 + lane * 2];
    float y0 = ((v.x - mu) * rstd * g.x + be.x) * silu_(z.x);
    float y1 = ((v.y - mu) * rstd * g.y + be.y) * silu_(z.y);
    yy[wid][lane * 2] = y0; yy[wid][lane * 2 + 1] = y1;
    __syncthreads();
    float acc = 0.f;
    const float* yrow = yy[wid];
    #pragma unroll 4
    for (int d = 0; d < 128; ++d) acc = fmaf(yrow[d], wt[d * 65 + lane], acc);
    y2[(size_t)m * 64 + lane] = acc;
}

// ---------------- K7: avg-pool(50,15) + classifier ----------------
__global__ __launch_bounds__(256) void k7_cls(
    const float* __restrict__ y2, const float* __restrict__ wcls,
    const float* __restrict__ clsb, float* __restrict__ out)
{
    __shared__ float pl[64 * 65];
    __shared__ float red[4][4];
    const int b = blockIdx.x, idx = threadIdx.x;
    const int o = idx & 63, pg = idx >> 6;
    for (int p = pg; p < 64; p += 4) {
        float s = 0.f;
        int tb = p * 15;
        for (int j = 0; j < 50; ++j) s += y2[(size_t)(b * T_ + tb + j) * 64 + o];
        pl[p * 65 + o] = s * 0.02f;
    }
    __syncthreads();
    float acc[4] = {0.f, 0.f, 0.f, 0.f};
    for (int f = idx; f < 4096; f += 256) {
        int oo = f >> 6, pp = f & 63;
        float v = pl[pp * 65 + oo];
        #pragma unroll
        for (int c = 0; c < 4; ++c) acc[c] = fmaf(wcls[c * 4096 + f], v, acc[c]);
    }
    const int wid = idx >> 6, lane = idx & 63;
    #pragma unroll
    for (int c = 0; c < 4; ++c) {
        float a = acc[c];
        #pragma unroll
        for (int off = 32; off; off >>= 1) a += __shfl_xor(a, off);
        if (lane == 0) red[wid][c] = a;
    }
    __syncthreads();
    if (idx < 4)
        out[b * 4 + idx] = red[0][idx] + red[1][idx] + red[2][idx] + red[3][idx] + clsb[idx];
}

// ---------------- launch ----------------
extern "C" void kernel_launch(void* const* d_in, const int* in_sizes, int n_in,
                              void* d_out, int out_size, void* d_ws, size_t ws_size,
                              hipStream_t stream) {
    if (ws_size < WS_FLOATS * sizeof(float)) return;   // clean failure instead of OOB fault

    const float* x        = (const float*)d_in[0];
    const float* sconv_w  = (const float*)d_in[1];
    const float* bn1_g    = (const float*)d_in[2];
    const float* bn1_b    = (const float*)d_in[3];
    const float* bn1_m    = (const float*)d_in[4];
    const float* bn1_v    = (const float*)d_in[5];
    const float* enc_w    = (const float*)d_in[6];
    const float* enc_b    = (const float*)d_in[7];
    const float* bn2_g    = (const float*)d_in[8];
    const float* bn2_b    = (const float*)d_in[9];
    const float* bn2_m    = (const float*)d_in[10];
    const float* bn2_v    = (const float*)d_in[11];
    const float* in_proj_w= (const float*)d_in[12];
    const float* conv1d_w = (const float*)d_in[13];
    const float* conv1d_b = (const float*)d_in[14];
    const float* x_proj_w = (const float*)d_in[15];
    const float* dt_proj_w= (const float*)d_in[16];
    const float* dt_proj_b= (const float*)d_in[17];
    const float* A_log    = (const float*)d_in[18];
    const float* Dp       = (const float*)d_in[19];
    const float* ln_g     = (const float*)d_in[20];
    const float* ln_b     = (const float*)d_in[21];
    const float* out_proj_w=(const float*)d_in[22];
    const float* cls_w    = (const float*)d_in[23];
    const float* cls_b    = (const float*)d_in[24];

    float* ws = (float*)d_ws;
    float* Mmat  = ws + OFF_M;
    float* bias2 = ws + OFF_B2;
    float* Weff  = ws + OFF_WEFF;
    float* beff  = ws + OFF_BEFF;
    float* A2    = ws + OFF_A2;
    float* wcls  = ws + OFF_WCLS;
    float* x2    = ws + OFF_X2;     // later reused as y2
    float* xz    = ws + OFF_XZ;     // xs half becomes du; z half read in K6
    float* u     = ws + OFF_U;
    float* delta = ws + OFF_DELTA;  // scan writes y in-place here
    float* Bmb   = ws + OFF_BM;
    float* Cmb   = ws + OFF_CM;

    hipLaunchKernelGGL(k0_prep, dim3(1), dim3(256), 0, stream,
        sconv_w, bn1_g, bn1_b, bn1_m, bn1_v, enc_w, enc_b, bn2_g, bn2_b, bn2_m, bn2_v,
        x_proj_w, dt_proj_w, dt_proj_b, A_log, cls_w,
        Mmat, bias2, Weff, beff, A2, wcls);

    hipLaunchKernelGGL(k1_frontend, dim3(32 * 32), dim3(256), 0, stream, x, Mmat, bias2, x2);
    hipLaunchKernelGGL(k2_inproj, dim3(500 * 4), dim3(256), 0, stream, x2, in_proj_w, xz);
    hipLaunchKernelGGL(k3_conv, dim3(4000), dim3(256), 0, stream, xz, conv1d_w, conv1d_b, u);
    hipLaunchKernelGGL(k4_xproj, dim3(500 * 3), dim3(256), 0, stream, u, Weff, beff, delta, xz, Bmb, Cmb);
    hipLaunchKernelGGL(k5_scan, dim3(256), dim3(256), 0, stream, delta, xz, u, Bmb, Cmb, A2, Dp);
    hipLaunchKernelGGL(k6_out, dim3(8000), dim3(256), 0, stream, delta, xz, ln_g, ln_b, out_proj_w, x2);
    hipLaunchKernelGGL(k7_cls, dim3(32), dim3(256), 0, stream, x2, wcls, cls_b, d_out ? (float*)d_out : nullptr);
}

// Round 3
// 452.559 us; speedup vs baseline: 2.1382x; 2.1382x over previous
//
#include <hip/hip_runtime.h>
#include <math.h>

#define B_ 32
#define T_ 1000
#define M_ 32000   // B_*T_
#define CCH 8      // scan chunks
#define LCH 125    // steps per chunk

// ---------------- workspace layout (float offsets) ----------------
constexpr size_t OFF_M     = 0;                       // 64*44
constexpr size_t OFF_B2    = 2816;                    // 64
constexpr size_t OFF_WEFF  = 2880;                    // 160*128
constexpr size_t OFF_BEFF  = 23360;                   // 160
constexpr size_t OFF_A2    = 23520;                   // 128*16
constexpr size_t OFF_WCLS  = 25568;                   // 4*4096
constexpr size_t OFF_X2    = 41952;                   // 32000*64   (also y2 after K6)
constexpr size_t OFF_XZ    = OFF_X2    + 2048000;     // 32000*256  (xs half -> du after K4; z half)
constexpr size_t OFF_U     = OFF_XZ    + 8192000;     // 32000*128
constexpr size_t OFF_DELTA = OFF_U     + 4096000;     // 32000*128  (scan overwrites with y in-place)
constexpr size_t OFF_BM    = OFF_DELTA + 4096000;     // 32000*16
constexpr size_t OFF_CM    = OFF_BM    + 512000;      // 32000*16
constexpr size_t OFF_P     = OFF_CM    + 512000;      // 32*8*2048 = 524288
constexpr size_t OFF_F     = OFF_P     + 524288;
constexpr size_t OFF_H     = OFF_F     + 524288;
constexpr size_t WS_FLOATS = OFF_H     + 524288;      // ~21.1M floats ≈ 84 MB

__device__ __forceinline__ float sigm_(float x)  { return 1.f / (1.f + __expf(-x)); }
__device__ __forceinline__ float silu_(float x)  { return x * sigm_(x); }
__device__ __forceinline__ float softp_(float x) { return fmaxf(x, 0.f) + log1pf(__expf(-fabsf(x))); }

// ---------------- K0: fold all small params ----------------
__global__ __launch_bounds__(256) void k0_prep(
    const float* __restrict__ sconv_w, const float* __restrict__ bn1_g, const float* __restrict__ bn1_b,
    const float* __restrict__ bn1_m, const float* __restrict__ bn1_v,
    const float* __restrict__ enc_w, const float* __restrict__ enc_b,
    const float* __restrict__ bn2_g, const float* __restrict__ bn2_b,
    const float* __restrict__ bn2_m, const float* __restrict__ bn2_v,
    const float* __restrict__ xpw, const float* __restrict__ dtw, const float* __restrict__ dtb,
    const float* __restrict__ A_log, const float* __restrict__ cls_w,
    float* __restrict__ Mmat, float* __restrict__ bias2, float* __restrict__ Weff,
    float* __restrict__ beff, float* __restrict__ A2, float* __restrict__ wcls)
{
    __shared__ float s1[128], b1[128], s2[64], b2f[64];
    const int idx = threadIdx.x;
    if (idx < 128) {
        float s = bn1_g[idx] * rsqrtf(bn1_v[idx] + 1e-5f);
        s1[idx] = s; b1[idx] = bn1_b[idx] - bn1_m[idx] * s;
    }
    if (idx < 64) {
        float s = bn2_g[idx] * rsqrtf(bn2_v[idx] + 1e-5f);
        s2[idx] = s; b2f[idx] = bn2_b[idx] - bn2_m[idx] * s;
    }
    __syncthreads();

    // folded frontend matrix M[o][j], j in [0,44): group g=j/22, tap i=j%22
    for (int e = idx; e < 64 * 44; e += 256) {
        int o = e / 44, j = e % 44, g = j / 22, i = j % 22;
        float acc = 0.f;
        for (int cc = 0; cc < 64; ++cc) {
            int c = g * 64 + cc;
            float ew = enc_w[(o * 64 + cc) * 2 + g];
            acc += ew * s1[c] * sconv_w[c * 22 + i];
        }
        Mmat[e] = acc * s2[o];
    }
    if (idx < 64) {
        int o = idx; float acc = 0.f;
        for (int c = 0; c < 128; ++c) {
            int g = c >> 6, i = c & 63;
            acc += enc_w[(o * 64 + i) * 2 + g] * b1[c];
        }
        bias2[o] = s2[o] * (acc + enc_b[o]) + b2f[o];
    }
    // Weff rows 0..127 = dt_proj_w @ x_proj_w[0:4]
    for (int e = idx; e < 128 * 128; e += 256) {
        int d = e >> 7, k = e & 127;
        float acc = 0.f;
        #pragma unroll
        for (int r = 0; r < 4; ++r) acc += dtw[d * 4 + r] * xpw[r * 128 + k];
        Weff[e] = acc;
    }
    // rows 128..159 = x_proj rows 4..35 (B then C)
    for (int e = idx; e < 32 * 128; e += 256) {
        int q = e >> 7, k = e & 127;
        Weff[128 * 128 + e] = xpw[(4 + q) * 128 + k];
    }
    if (idx < 160) beff[idx] = (idx < 128) ? dtb[idx] : 0.f;

    const float LOG2E = 1.4426950408889634f;
    for (int e = idx; e < 2048; e += 256) A2[e] = -expf(A_log[e]) * LOG2E;

    // normalized classifier weights
    int wid = idx >> 6, lane = idx & 63;
    for (int c = wid; c < 4; c += 4) {
        float p = 0.f;
        for (int f = lane; f < 4096; f += 64) { float v = cls_w[c * 4096 + f]; p += v * v; }
        #pragma unroll
        for (int off = 32; off; off >>= 1) p += __shfl_xor(p, off);
        float sc = fminf(1.f, 0.5f / (sqrtf(p) + 1e-7f));
        for (int f = lane; f < 4096; f += 64) wcls[c * 4096 + f] = cls_w[c * 4096 + f] * sc;
    }
}

// ---------------- K1: folded frontend GEMM 44 -> 64 ----------------
__global__ __launch_bounds__(256) void k1_frontend(
    const float* __restrict__ x, const float* __restrict__ Mmat,
    const float* __restrict__ bias2, float* __restrict__ x2)
{
    __shared__ float Ml[64 * 44];
    __shared__ float xl[44][32];
    const int b = blockIdx.x >> 5, tile = blockIdx.x & 31;
    const int t0 = tile * 32;
    const int idx = threadIdx.x;
    for (int e = idx; e < 64 * 44; e += 256) Ml[e] = Mmat[e];
    {
        int i = idx & 31, j0 = idx >> 5;
        for (int j = j0; j < 44; j += 8) {
            int t = t0 + i;
            xl[j][i] = (t < T_) ? x[(b * 44 + j) * T_ + t] : 0.f;
        }
    }
    __syncthreads();
    const int tl = idx & 31, os = idx >> 5;
    const int t = t0 + tl;
    if (t >= T_) return;
    float acc[8];
    #pragma unroll
    for (int q = 0; q < 8; ++q) acc[q] = bias2[os * 8 + q];
    for (int j = 0; j < 44; ++j) {
        float xv = xl[j][tl];
        #pragma unroll
        for (int q = 0; q < 8; ++q) acc[q] = fmaf(Ml[(os * 8 + q) * 44 + j], xv, acc[q]);
    }
    float4* dst = (float4*)&x2[((size_t)(b * T_ + t)) * 64 + os * 8];
    dst[0] = make_float4(acc[0], acc[1], acc[2], acc[3]);
    dst[1] = make_float4(acc[4], acc[5], acc[6], acc[7]);
}

// ---------------- K2: in_proj GEMM 64 -> 256 ----------------
__global__ __launch_bounds__(256) void k2_inproj(
    const float* __restrict__ x2, const float* __restrict__ W, float* __restrict__ xz)
{
    __shared__ float al[64 * 68];
    __shared__ float bl[64 * 68];
    const int mt = blockIdx.x >> 2, nt = blockIdx.x & 3;
    const int m0 = mt * 64, n0 = nt * 64;
    const int idx = threadIdx.x;
    {
        int mp = idx >> 2, kq = idx & 3;
        #pragma unroll
        for (int f = 0; f < 4; ++f) {
            int k = kq * 16 + f * 4;
            float4 v = *(const float4*)&x2[(size_t)(m0 + mp) * 64 + k];
            al[(k + 0) * 68 + mp] = v.x; al[(k + 1) * 68 + mp] = v.y;
            al[(k + 2) * 68 + mp] = v.z; al[(k + 3) * 68 + mp] = v.w;
            float4 w = *(const float4*)&W[(size_t)(n0 + mp) * 64 + k];
            bl[(k + 0) * 68 + mp] = w.x; bl[(k + 1) * 68 + mp] = w.y;
            bl[(k + 2) * 68 + mp] = w.z; bl[(k + 3) * 68 + mp] = w.w;
        }
    }
    __syncthreads();
    const int ti = idx >> 4, ni = idx & 15;
    float acc[4][4] = {};
    for (int k = 0; k < 64; ++k) {
        float4 a = *(const float4*)&al[k * 68 + ti * 4];
        float4 w = *(const float4*)&bl[k * 68 + ni * 4];
        float av[4] = {a.x, a.y, a.z, a.w};
        float wv[4] = {w.x, w.y, w.z, w.w};
        #pragma unroll
        for (int r = 0; r < 4; ++r)
            #pragma unroll
            for (int c = 0; c < 4; ++c) acc[r][c] = fmaf(av[r], wv[c], acc[r][c]);
    }
    #pragma unroll
    for (int r = 0; r < 4; ++r)
        *(float4*)&xz[(size_t)(m0 + ti * 4 + r) * 256 + n0 + ni * 4] =
            make_float4(acc[r][0], acc[r][1], acc[r][2], acc[r][3]);
}

// ---------------- K3: depthwise conv1d(3) + silu -> u ----------------
__global__ __launch_bounds__(256) void k3_conv(
    const float* __restrict__ xz, const float* __restrict__ cw,
    const float* __restrict__ cb, float* __restrict__ u)
{
    const int gid = blockIdx.x * 256 + threadIdx.x;   // 32000*32
    const int m = gid >> 5, d4 = gid & 31;
    const int t = m % T_;
    const int d0 = d4 * 4;
    float4 z4 = make_float4(0.f, 0.f, 0.f, 0.f);
    float4 vm = (t > 0)      ? *(const float4*)&xz[(size_t)(m - 1) * 256 + d0] : z4;
    float4 v0 =                *(const float4*)&xz[(size_t)(m)     * 256 + d0];
    float4 vp = (t < T_ - 1) ? *(const float4*)&xz[(size_t)(m + 1) * 256 + d0] : z4;
    const float* pm = (const float*)&vm;
    const float* p0 = (const float*)&v0;
    const float* pp = (const float*)&vp;
    float r[4];
    #pragma unroll
    for (int e = 0; e < 4; ++e) {
        int d = d0 + e;
        float a = pm[e] * cw[d * 3 + 0] + p0[e] * cw[d * 3 + 1] + pp[e] * cw[d * 3 + 2] + cb[d];
        r[e] = silu_(a);
    }
    *(float4*)&u[(size_t)m * 128 + d0] = make_float4(r[0], r[1], r[2], r[3]);
}

// ---------------- K4: fused x_proj+dt GEMM 128 -> 160 (+softplus, du, B, C) ----------------
__global__ __launch_bounds__(256) void k4_xproj(
    const float* __restrict__ u, const float* __restrict__ Weff, const float* __restrict__ beff,
    float* __restrict__ delta, float* __restrict__ xz /* du dest, stride 256 */,
    float* __restrict__ Bm, float* __restrict__ Cm)
{
    __shared__ float al[64 * 68];
    __shared__ float bl[64 * 68];
    const int mt = blockIdx.x / 3, nt = blockIdx.x % 3;
    const int m0 = mt * 64, n0 = nt * 64;
    const int idx = threadIdx.x;
    const int ti = idx >> 4, ni = idx & 15;
    float acc[4][4] = {};
    for (int kb = 0; kb < 128; kb += 64) {
        __syncthreads();
        {
            int mp = idx >> 2, kq = idx & 3;
            #pragma unroll
            for (int f = 0; f < 4; ++f) {
                int k = kq * 16 + f * 4;
                float4 v = *(const float4*)&u[(size_t)(m0 + mp) * 128 + kb + k];
                al[(k + 0) * 68 + mp] = v.x; al[(k + 1) * 68 + mp] = v.y;
                al[(k + 2) * 68 + mp] = v.z; al[(k + 3) * 68 + mp] = v.w;
                int row = n0 + mp;
                float4 w = (row < 160) ? *(const float4*)&Weff[(size_t)row * 128 + kb + k]
                                       : make_float4(0.f, 0.f, 0.f, 0.f);
                bl[(k + 0) * 68 + mp] = w.x; bl[(k + 1) * 68 + mp] = w.y;
                bl[(k + 2) * 68 + mp] = w.z; bl[(k + 3) * 68 + mp] = w.w;
            }
        }
        __syncthreads();
        for (int k = 0; k < 64; ++k) {
            float4 a = *(const float4*)&al[k * 68 + ti * 4];
            float4 w = *(const float4*)&bl[k * 68 + ni * 4];
            float av[4] = {a.x, a.y, a.z, a.w};
            float wv[4] = {w.x, w.y, w.z, w.w};
            #pragma unroll
            for (int r = 0; r < 4; ++r)
                #pragma unroll
                for (int c = 0; c < 4; ++c) acc[r][c] = fmaf(av[r], wv[c], acc[r][c]);
        }
    }
    if (nt < 2) {
        #pragma unroll
        for (int r = 0; r < 4; ++r) {
            int m = m0 + ti * 4 + r;
            float4 uv = *(const float4*)&u[(size_t)m * 128 + n0 + ni * 4];
            const float* up = (const float*)&uv;
            float dl[4];
            #pragma unroll
            for (int c = 0; c < 4; ++c) {
                int n = n0 + ni * 4 + c;
                dl[c] = softp_(acc[r][c] + beff[n]);
            }
            *(float4*)&delta[(size_t)m * 128 + n0 + ni * 4] = make_float4(dl[0], dl[1], dl[2], dl[3]);
            *(float4*)&xz[(size_t)m * 256 + n0 + ni * 4] =
                make_float4(dl[0] * up[0], dl[1] * up[1], dl[2] * up[2], dl[3] * up[3]);
        }
    } else if (ni < 8) {
        float* dst = (ni < 4) ? Bm : Cm;
        int q0 = (ni & 3) * 4;
        #pragma unroll
        for (int r = 0; r < 4; ++r) {
            int m = m0 + ti * 4 + r;
            #pragma unroll
            for (int c = 0; c < 4; ++c) dst[(size_t)m * 16 + q0 + c] = acc[r][c];
        }
    }
}

// ---------------- K5a: scan pass 1 — per-chunk propagator P and local final F ----------------
__global__ __launch_bounds__(256) void k5a_scan1(
    const float* __restrict__ delta, const float* __restrict__ du /* stride 256 */,
    const float* __restrict__ Bm, const float* __restrict__ A2,
    float* __restrict__ Pbuf, float* __restrict__ Fbuf)
{
    const int bc = blockIdx.x >> 3;                       // b*CCH + c
    const int b = bc >> 3, c = bc & (CCH - 1);
    const int r = ((blockIdx.x & 7) << 8) | threadIdx.x;  // 0..2047
    const int d = r >> 4, n = r & 15;
    const float a2 = A2[d * 16 + n];
    const int t0 = c * LCH;
    const float* dptr  = delta + ((size_t)b * T_ + t0) * 128 + d;
    const float* duptr = du    + ((size_t)b * T_ + t0) * 256 + d;
    const float* bptr  = Bm    + ((size_t)b * T_ + t0) * 16  + n;
    float h = 0.f, P = 1.f;
    #pragma unroll 5
    for (int t = 0; t < LCH; ++t) {
        float dl  = dptr[(size_t)t * 128];
        float duv = duptr[(size_t)t * 256];
        float bcv = bptr[(size_t)t * 16];
        float dA  = exp2f(dl * a2);
        h = fmaf(dA, h, duv * bcv);
        P *= dA;
    }
    Pbuf[(size_t)bc * 2048 + r] = P;
    Fbuf[(size_t)bc * 2048 + r] = h;
}

// ---------------- K5b: scan pass 2 — carry scan over chunks ----------------
__global__ __launch_bounds__(256) void k5b_carry(
    const float* __restrict__ Pbuf, const float* __restrict__ Fbuf, float* __restrict__ Hin)
{
    const int tid = blockIdx.x * 256 + threadIdx.x;       // 65536 threads
    const int b = tid >> 11, r = tid & 2047;
    float h = 0.f;
    #pragma unroll
    for (int c = 0; c < CCH; ++c) {
        size_t i = ((size_t)(b * CCH + c)) * 2048 + r;
        Hin[i] = h;                                       // incoming state for chunk c
        h = fmaf(Pbuf[i], h, Fbuf[i]);
    }
}

// ---------------- K5c: scan pass 3 — full scan per chunk with carried h (y in-place over delta) --
__global__ __launch_bounds__(256) void k5c_scan2(
    float* dy /* delta in, y out — NOT restrict (aliased) */,
    const float* __restrict__ du /* stride 256 */,
    const float* __restrict__ u, const float* __restrict__ Bm, const float* __restrict__ Cm,
    const float* __restrict__ A2, const float* __restrict__ Dp, const float* __restrict__ Hin)
{
    const int bc = blockIdx.x >> 3;
    const int b = bc >> 3, c = bc & (CCH - 1);
    const int r = ((blockIdx.x & 7) << 8) | threadIdx.x;
    const int d = r >> 4, n = r & 15;
    const float a2 = A2[d * 16 + n];
    const float dpv = Dp[d];
    const bool wr = (n == 0);
    const int t0 = c * LCH;
    float h = Hin[(size_t)bc * 2048 + r];
    float*       dptr  = dy + ((size_t)b * T_ + t0) * 128 + d;
    const float* duptr = du + ((size_t)b * T_ + t0) * 256 + d;
    const float* uptr  = u  + ((size_t)b * T_ + t0) * 128 + d;
    const float* bptr  = Bm + ((size_t)b * T_ + t0) * 16  + n;
    const float* cptr  = Cm + ((size_t)b * T_ + t0) * 16  + n;
    #pragma unroll 5
    for (int t = 0; t < LCH; ++t) {
        float dl  = dptr[(size_t)t * 128];
        float duv = duptr[(size_t)t * 256];
        float bcv = bptr[(size_t)t * 16];
        float ccv = cptr[(size_t)t * 16];
        float dA  = exp2f(dl * a2);
        h = fmaf(dA, h, duv * bcv);
        float p = h * ccv;
        p += __shfl_xor(p, 1);
        p += __shfl_xor(p, 2);
        p += __shfl_xor(p, 4);
        p += __shfl_xor(p, 8);
        if (wr) dptr[(size_t)t * 128] = fmaf(uptr[(size_t)t * 128], dpv, p);
    }
}

// ---------------- K6: LayerNorm + silu(z) gate + out_proj 128 -> 64 ----------------
__global__ __launch_bounds__(256) void k6_out(
    const float* __restrict__ ys, const float* __restrict__ xz,
    const float* __restrict__ lng, const float* __restrict__ lnb,
    const float* __restrict__ Wout, float* __restrict__ y2)
{
    __shared__ float wt[128 * 65];
    __shared__ float yy[4][128];
    const int idx = threadIdx.x;
    for (int f = idx; f < 64 * 128; f += 256) {
        int o = f >> 7, d = f & 127;
        wt[d * 65 + o] = Wout[f];
    }
    const int wid = idx >> 6, lane = idx & 63;
    const int m = blockIdx.x * 4 + wid;
    float2 v = *(const float2*)&ys[(size_t)m * 128 + lane * 2];
    float s = v.x + v.y;
    float sq = v.x * v.x + v.y * v.y;
    #pragma unroll
    for (int off = 32; off; off >>= 1) { s += __shfl_xor(s, off); sq += __shfl_xor(sq, off); }
    float mu = s * (1.f / 128.f);
    float var = sq * (1.f / 128.f) - mu * mu;
    float rstd = rsqrtf(var + 1e-5f);
    float2 g  = *(const float2*)&lng[lane * 2];
    float2 be = *(const float2*)&lnb[lane * 2];
    float2 z  = *(const float2*)&xz[(size_t)m * 256 + 128 + lane * 2];
    float y0 = ((v.x - mu) * rstd * g.x + be.x) * silu_(z.x);
    float y1 = ((v.y - mu) * rstd * g.y + be.y) * silu_(z.y);
    yy[wid][lane * 2] = y0; yy[wid][lane * 2 + 1] = y1;
    __syncthreads();
    float acc = 0.f;
    const float* yrow = yy[wid];
    #pragma unroll 4
    for (int d = 0; d < 128; ++d) acc = fmaf(yrow[d], wt[d * 65 + lane], acc);
    y2[(size_t)m * 64 + lane] = acc;
}

// ---------------- K7: avg-pool(50,15) + classifier ----------------
__global__ __launch_bounds__(256) void k7_cls(
    const float* __restrict__ y2, const float* __restrict__ wcls,
    const float* __restrict__ clsb, float* __restrict__ out)
{
    __shared__ float pl[64 * 65];
    __shared__ float red[4][4];
    const int b = blockIdx.x, idx = threadIdx.x;
    const int o = idx & 63, pg = idx >> 6;
    for (int p = pg; p < 64; p += 4) {
        float s = 0.f;
        int tb = p * 15;
        for (int j = 0; j < 50; ++j) s += y2[(size_t)(b * T_ + tb + j) * 64 + o];
        pl[p * 65 + o] = s * 0.02f;
    }
    __syncthreads();
    float acc[4] = {0.f, 0.f, 0.f, 0.f};
    for (int f = idx; f < 4096; f += 256) {
        int oo = f >> 6, pp = f & 63;
        float v = pl[pp * 65 + oo];
        #pragma unroll
        for (int c = 0; c < 4; ++c) acc[c] = fmaf(wcls[c * 4096 + f], v, acc[c]);
    }
    const int wid = idx >> 6, lane = idx & 63;
    #pragma unroll
    for (int c = 0; c < 4; ++c) {
        float a = acc[c];
        #pragma unroll
        for (int off = 32; off; off >>= 1) a += __shfl_xor(a, off);
        if (lane == 0) red[wid][c] = a;
    }
    __syncthreads();
    if (idx < 4)
        out[b * 4 + idx] = red[0][idx] + red[1][idx] + red[2][idx] + red[3][idx] + clsb[idx];
}

// ---------------- launch ----------------
extern "C" void kernel_launch(void* const* d_in, const int* in_sizes, int n_in,
                              void* d_out, int out_size, void* d_ws, size_t ws_size,
                              hipStream_t stream) {
    if (ws_size < WS_FLOATS * sizeof(float)) return;   // clean failure instead of OOB fault

    const float* x        = (const float*)d_in[0];
    const float* sconv_w  = (const float*)d_in[1];
    const float* bn1_g    = (const float*)d_in[2];
    const float* bn1_b    = (const float*)d_in[3];
    const float* bn1_m    = (const float*)d_in[4];
    const float* bn1_v    = (const float*)d_in[5];
    const float* enc_w    = (const float*)d_in[6];
    const float* enc_b    = (const float*)d_in[7];
    const float* bn2_g    = (const float*)d_in[8];
    const float* bn2_b    = (const float*)d_in[9];
    const float* bn2_m    = (const float*)d_in[10];
    const float* bn2_v    = (const float*)d_in[11];
    const float* in_proj_w= (const float*)d_in[12];
    const float* conv1d_w = (const float*)d_in[13];
    const float* conv1d_b = (const float*)d_in[14];
    const float* x_proj_w = (const float*)d_in[15];
    const float* dt_proj_w= (const float*)d_in[16];
    const float* dt_proj_b= (const float*)d_in[17];
    const float* A_log    = (const float*)d_in[18];
    const float* Dp       = (const float*)d_in[19];
    const float* ln_g     = (const float*)d_in[20];
    const float* ln_b     = (const float*)d_in[21];
    const float* out_proj_w=(const float*)d_in[22];
    const float* cls_w    = (const float*)d_in[23];
    const float* cls_b    = (const float*)d_in[24];

    float* ws = (float*)d_ws;
    float* Mmat  = ws + OFF_M;
    float* bias2 = ws + OFF_B2;
    float* Weff  = ws + OFF_WEFF;
    float* beff  = ws + OFF_BEFF;
    float* A2    = ws + OFF_A2;
    float* wcls  = ws + OFF_WCLS;
    float* x2    = ws + OFF_X2;     // later reused as y2
    float* xz    = ws + OFF_XZ;     // xs half becomes du; z half read in K6
    float* u     = ws + OFF_U;
    float* delta = ws + OFF_DELTA;  // scan writes y in-place here
    float* Bmb   = ws + OFF_BM;
    float* Cmb   = ws + OFF_CM;
    float* Pbuf  = ws + OFF_P;
    float* Fbuf  = ws + OFF_F;
    float* Hin   = ws + OFF_H;

    hipLaunchKernelGGL(k0_prep, dim3(1), dim3(256), 0, stream,
        sconv_w, bn1_g, bn1_b, bn1_m, bn1_v, enc_w, enc_b, bn2_g, bn2_b, bn2_m, bn2_v,
        x_proj_w, dt_proj_w, dt_proj_b, A_log, cls_w,
        Mmat, bias2, Weff, beff, A2, wcls);

    hipLaunchKernelGGL(k1_frontend, dim3(32 * 32), dim3(256), 0, stream, x, Mmat, bias2, x2);
    hipLaunchKernelGGL(k2_inproj, dim3(500 * 4), dim3(256), 0, stream, x2, in_proj_w, xz);
    hipLaunchKernelGGL(k3_conv, dim3(4000), dim3(256), 0, stream, xz, conv1d_w, conv1d_b, u);
    hipLaunchKernelGGL(k4_xproj, dim3(500 * 3), dim3(256), 0, stream, u, Weff, beff, delta, xz, Bmb, Cmb);
    hipLaunchKernelGGL(k5a_scan1, dim3(B_ * CCH * 8), dim3(256), 0, stream, delta, xz, Bmb, A2, Pbuf, Fbuf);
    hipLaunchKernelGGL(k5b_carry, dim3(256), dim3(256), 0, stream, Pbuf, Fbuf, Hin);
    hipLaunchKernelGGL(k5c_scan2, dim3(B_ * CCH * 8), dim3(256), 0, stream, delta, xz, u, Bmb, Cmb, A2, Dp, Hin);
    hipLaunchKernelGGL(k6_out, dim3(8000), dim3(256), 0, stream, delta, xz, ln_g, ln_b, out_proj_w, x2);
    hipLaunchKernelGGL(k7_cls, dim3(32), dim3(256), 0, stream, x2, wcls, cls_b, d_out ? (float*)d_out : nullptr);
}

// Round 9
// 395.056 us; speedup vs baseline: 2.4494x; 1.1456x over previous
//
#include <hip/hip_runtime.h>
#include <math.h>

#define B_ 32
#define T_ 1000
#define M_ 32000   // B_*T_
#define CCH 50     // scan chunks
#define LCH 20     // steps per chunk (CCH*LCH == T_)

// ---------------- workspace layout (float offsets) ----------------
constexpr size_t OFF_M     = 0;                       // 64*44
constexpr size_t OFF_B2    = 2816;                    // 64
constexpr size_t OFF_WEFF  = 2880;                    // 160*128
constexpr size_t OFF_BEFF  = 23360;                   // 160
constexpr size_t OFF_A2    = 23520;                   // 16*128 (transposed: [n][d])
constexpr size_t OFF_WCLS  = 25568;                   // 4*4096
constexpr size_t OFF_X2    = 41952;                   // 32000*64   (also y2 after K6)
constexpr size_t OFF_XZ    = OFF_X2 + 2048000;        // 32000*256: xs->delta->y ; z half
constexpr size_t OFF_U     = OFF_XZ + 8192000;        // 32000*128
constexpr size_t OFF_F     = OFF_U  + 4096000;        // 32*50*16*128 = 3,276,800 (F, then Hin)
constexpr size_t OFF_D     = OFF_F  + 3276800;        // 32*50*128    =   204,800 (sum-delta)
constexpr size_t OFF_BM    = OFF_D  + 204800;         // 32000*16
constexpr size_t OFF_CM    = OFF_BM + 512000;         // 32000*16
constexpr size_t WS_FLOATS = OFF_CM + 512000;         // 18,883,552 floats ≈ 75.5 MB (≤ proven 78)

__device__ __forceinline__ float sigm_(float x)  { return 1.f / (1.f + __expf(-x)); }
__device__ __forceinline__ float silu_(float x)  { return x * sigm_(x); }
__device__ __forceinline__ float softp_(float x) { return fmaxf(x, 0.f) + log1pf(__expf(-fabsf(x))); }

// ---------------- K0: fold all small params ----------------
__global__ __launch_bounds__(256) void k0_prep(
    const float* __restrict__ sconv_w, const float* __restrict__ bn1_g, const float* __restrict__ bn1_b,
    const float* __restrict__ bn1_m, const float* __restrict__ bn1_v,
    const float* __restrict__ enc_w, const float* __restrict__ enc_b,
    const float* __restrict__ bn2_g, const float* __restrict__ bn2_b,
    const float* __restrict__ bn2_m, const float* __restrict__ bn2_v,
    const float* __restrict__ xpw, const float* __restrict__ dtw, const float* __restrict__ dtb,
    const float* __restrict__ A_log, const float* __restrict__ cls_w,
    float* __restrict__ Mmat, float* __restrict__ bias2, float* __restrict__ Weff,
    float* __restrict__ beff, float* __restrict__ A2T, float* __restrict__ wcls)
{
    __shared__ float s1[128], b1[128], s2[64], b2f[64];
    const int idx = threadIdx.x;
    if (idx < 128) {
        float s = bn1_g[idx] * rsqrtf(bn1_v[idx] + 1e-5f);
        s1[idx] = s; b1[idx] = bn1_b[idx] - bn1_m[idx] * s;
    }
    if (idx < 64) {
        float s = bn2_g[idx] * rsqrtf(bn2_v[idx] + 1e-5f);
        s2[idx] = s; b2f[idx] = bn2_b[idx] - bn2_m[idx] * s;
    }
    __syncthreads();

    // folded frontend matrix M[o][j], j in [0,44): group g=j/22, tap i=j%22
    for (int e = idx; e < 64 * 44; e += 256) {
        int o = e / 44, j = e % 44, g = j / 22, i = j % 22;
        float acc = 0.f;
        for (int cc = 0; cc < 64; ++cc) {
            int c = g * 64 + cc;
            float ew = enc_w[(o * 64 + cc) * 2 + g];
            acc += ew * s1[c] * sconv_w[c * 22 + i];
        }
        Mmat[e] = acc * s2[o];
    }
    if (idx < 64) {
        int o = idx; float acc = 0.f;
        for (int c = 0; c < 128; ++c) {
            int g = c >> 6, i = c & 63;
            acc += enc_w[(o * 64 + i) * 2 + g] * b1[c];
        }
        bias2[o] = s2[o] * (acc + enc_b[o]) + b2f[o];
    }
    // Weff rows 0..127 = dt_proj_w @ x_proj_w[0:4]
    for (int e = idx; e < 128 * 128; e += 256) {
        int d = e >> 7, k = e & 127;
        float acc = 0.f;
        #pragma unroll
        for (int r = 0; r < 4; ++r) acc += dtw[d * 4 + r] * xpw[r * 128 + k];
        Weff[e] = acc;
    }
    // rows 128..159 = x_proj rows 4..35 (B then C)
    for (int e = idx; e < 32 * 128; e += 256) {
        int q = e >> 7, k = e & 127;
        Weff[128 * 128 + e] = xpw[(4 + q) * 128 + k];
    }
    if (idx < 160) beff[idx] = (idx < 128) ? dtb[idx] : 0.f;

    const float LOG2E = 1.4426950408889634f;
    // transposed A2T[n][d] = -exp(A_log[d][n]) * log2(e)
    for (int e = idx; e < 2048; e += 256) {
        int n = e >> 7, d = e & 127;
        A2T[e] = -expf(A_log[d * 16 + n]) * LOG2E;
    }

    // normalized classifier weights
    int wid = idx >> 6, lane = idx & 63;
    for (int c = wid; c < 4; c += 4) {
        float p = 0.f;
        for (int f = lane; f < 4096; f += 64) { float v = cls_w[c * 4096 + f]; p += v * v; }
        #pragma unroll
        for (int off = 32; off; off >>= 1) p += __shfl_xor(p, off);
        float sc = fminf(1.f, 0.5f / (sqrtf(p) + 1e-7f));
        for (int f = lane; f < 4096; f += 64) wcls[c * 4096 + f] = cls_w[c * 4096 + f] * sc;
    }
}

// ---------------- K1: folded frontend GEMM 44 -> 64 ----------------
__global__ __launch_bounds__(256) void k1_frontend(
    const float* __restrict__ x, const float* __restrict__ Mmat,
    const float* __restrict__ bias2, float* __restrict__ x2)
{
    __shared__ float Ml[64 * 44];
    __shared__ float xl[44][32];
    const int b = blockIdx.x >> 5, tile = blockIdx.x & 31;
    const int t0 = tile * 32;
    const int idx = threadIdx.x;
    for (int e = idx; e < 64 * 44; e += 256) Ml[e] = Mmat[e];
    {
        int i = idx & 31, j0 = idx >> 5;
        for (int j = j0; j < 44; j += 8) {
            int t = t0 + i;
            xl[j][i] = (t < T_) ? x[(b * 44 + j) * T_ + t] : 0.f;
        }
    }
    __syncthreads();
    const int tl = idx & 31, os = idx >> 5;
    const int t = t0 + tl;
    if (t >= T_) return;
    float acc[8];
    #pragma unroll
    for (int q = 0; q < 8; ++q) acc[q] = bias2[os * 8 + q];
    for (int j = 0; j < 44; ++j) {
        float xv = xl[j][tl];
        #pragma unroll
        for (int q = 0; q < 8; ++q) acc[q] = fmaf(Ml[(os * 8 + q) * 44 + j], xv, acc[q]);
    }
    float4* dst = (float4*)&x2[((size_t)(b * T_ + t)) * 64 + os * 8];
    dst[0] = make_float4(acc[0], acc[1], acc[2], acc[3]);
    dst[1] = make_float4(acc[4], acc[5], acc[6], acc[7]);
}

// ---------------- K2: in_proj GEMM 64 -> 256 ----------------
__global__ __launch_bounds__(256) void k2_inproj(
    const float* __restrict__ x2, const float* __restrict__ W, float* __restrict__ xz)
{
    __shared__ float al[64 * 68];
    __shared__ float bl[64 * 68];
    const int mt = blockIdx.x >> 2, nt = blockIdx.x & 3;
    const int m0 = mt * 64, n0 = nt * 64;
    const int idx = threadIdx.x;
    {
        int mp = idx >> 2, kq = idx & 3;
        #pragma unroll
        for (int f = 0; f < 4; ++f) {
            int k = kq * 16 + f * 4;
            float4 v = *(const float4*)&x2[(size_t)(m0 + mp) * 64 + k];
            al[(k + 0) * 68 + mp] = v.x; al[(k + 1) * 68 + mp] = v.y;
            al[(k + 2) * 68 + mp] = v.z; al[(k + 3) * 68 + mp] = v.w;
            float4 w = *(const float4*)&W[(size_t)(n0 + mp) * 64 + k];
            bl[(k + 0) * 68 + mp] = w.x; bl[(k + 1) * 68 + mp] = w.y;
            bl[(k + 2) * 68 + mp] = w.z; bl[(k + 3) * 68 + mp] = w.w;
        }
    }
    __syncthreads();
    const int ti = idx >> 4, ni = idx & 15;
    float acc[4][4] = {};
    for (int k = 0; k < 64; ++k) {
        float4 a = *(const float4*)&al[k * 68 + ti * 4];
        float4 w = *(const float4*)&bl[k * 68 + ni * 4];
        float av[4] = {a.x, a.y, a.z, a.w};
        float wv[4] = {w.x, w.y, w.z, w.w};
        #pragma unroll
        for (int r = 0; r < 4; ++r)
            #pragma unroll
            for (int c = 0; c < 4; ++c) acc[r][c] = fmaf(av[r], wv[c], acc[r][c]);
    }
    #pragma unroll
    for (int r = 0; r < 4; ++r)
        *(float4*)&xz[(size_t)(m0 + ti * 4 + r) * 256 + n0 + ni * 4] =
            make_float4(acc[r][0], acc[r][1], acc[r][2], acc[r][3]);
}

// ---------------- K3: depthwise conv1d(3) + silu -> u ----------------
__global__ __launch_bounds__(256) void k3_conv(
    const float* __restrict__ xz, const float* __restrict__ cw,
    const float* __restrict__ cb, float* __restrict__ u)
{
    const int gid = blockIdx.x * 256 + threadIdx.x;   // 32000*32
    const int m = gid >> 5, d4 = gid & 31;
    const int t = m % T_;
    const int d0 = d4 * 4;
    float4 z4 = make_float4(0.f, 0.f, 0.f, 0.f);
    float4 vm = (t > 0)      ? *(const float4*)&xz[(size_t)(m - 1) * 256 + d0] : z4;
    float4 v0 =                *(const float4*)&xz[(size_t)(m)     * 256 + d0];
    float4 vp = (t < T_ - 1) ? *(const float4*)&xz[(size_t)(m + 1) * 256 + d0] : z4;
    const float* pm = (const float*)&vm;
    const float* p0 = (const float*)&v0;
    const float* pp = (const float*)&vp;
    float r[4];
    #pragma unroll
    for (int e = 0; e < 4; ++e) {
        int d = d0 + e;
        float a = pm[e] * cw[d * 3 + 0] + p0[e] * cw[d * 3 + 1] + pp[e] * cw[d * 3 + 2] + cb[d];
        r[e] = silu_(a);
    }
    *(float4*)&u[(size_t)m * 128 + d0] = make_float4(r[0], r[1], r[2], r[3]);
}

// ---------------- K4: fused x_proj+dt GEMM 128 -> 160 (softplus -> delta into xz xs-half; B, C) --
__global__ __launch_bounds__(256) void k4_xproj(
    const float* __restrict__ u, const float* __restrict__ Weff, const float* __restrict__ beff,
    float* __restrict__ xz /* delta dest, stride 256 */,
    float* __restrict__ Bm, float* __restrict__ Cm)
{
    __shared__ float al[64 * 68];
    __shared__ float bl[64 * 68];
    const int mt = blockIdx.x / 3, nt = blockIdx.x % 3;
    const int m0 = mt * 64, n0 = nt * 64;
    const int idx = threadIdx.x;
    const int ti = idx >> 4, ni = idx & 15;
    float acc[4][4] = {};
    for (int kb = 0; kb < 128; kb += 64) {
        __syncthreads();
        {
            int mp = idx >> 2, kq = idx & 3;
            #pragma unroll
            for (int f = 0; f < 4; ++f) {
                int k = kq * 16 + f * 4;
                float4 v = *(const float4*)&u[(size_t)(m0 + mp) * 128 + kb + k];
                al[(k + 0) * 68 + mp] = v.x; al[(k + 1) * 68 + mp] = v.y;
                al[(k + 2) * 68 + mp] = v.z; al[(k + 3) * 68 + mp] = v.w;
                int row = n0 + mp;
                float4 w = (row < 160) ? *(const float4*)&Weff[(size_t)row * 128 + kb + k]
                                       : make_float4(0.f, 0.f, 0.f, 0.f);
                bl[(k + 0) * 68 + mp] = w.x; bl[(k + 1) * 68 + mp] = w.y;
                bl[(k + 2) * 68 + mp] = w.z; bl[(k + 3) * 68 + mp] = w.w;
            }
        }
        __syncthreads();
        for (int k = 0; k < 64; ++k) {
            float4 a = *(const float4*)&al[k * 68 + ti * 4];
            float4 w = *(const float4*)&bl[k * 68 + ni * 4];
            float av[4] = {a.x, a.y, a.z, a.w};
            float wv[4] = {w.x, w.y, w.z, w.w};
            #pragma unroll
            for (int r = 0; r < 4; ++r)
                #pragma unroll
                for (int c = 0; c < 4; ++c) acc[r][c] = fmaf(av[r], wv[c], acc[r][c]);
        }
    }
    if (nt < 2) {
        #pragma unroll
        for (int r = 0; r < 4; ++r) {
            int m = m0 + ti * 4 + r;
            float dl[4];
            #pragma unroll
            for (int c = 0; c < 4; ++c) {
                int n = n0 + ni * 4 + c;
                dl[c] = softp_(acc[r][c] + beff[n]);
            }
            *(float4*)&xz[(size_t)m * 256 + n0 + ni * 4] = make_float4(dl[0], dl[1], dl[2], dl[3]);
        }
    } else if (ni < 8) {
        float* dst = (ni < 4) ? Bm : Cm;
        int q0 = (ni & 3) * 4;
        #pragma unroll
        for (int r = 0; r < 4; ++r) {
            int m = m0 + ti * 4 + r;
            #pragma unroll
            for (int c = 0; c < 4; ++c) dst[(size_t)m * 16 + q0 + c] = acc[r][c];
        }
    }
}

// ---------------- K5a: pass 1 — per-chunk local final state F and sum-delta D ----------------
// lane owns one d; 16 states in registers; B row via wave-uniform (scalar) loads
__global__ __launch_bounds__(128) void k5a_scan1(
    const float* __restrict__ xz /* delta at [m*256+d] */, const float* __restrict__ u,
    const float* __restrict__ Bm, const float* __restrict__ A2T,
    float* __restrict__ Fbuf, float* __restrict__ Dbuf)
{
    const int b = blockIdx.x / CCH, c = blockIdx.x % CCH;
    const int d = threadIdx.x;
    float a2r[16];
    #pragma unroll
    for (int n = 0; n < 16; ++n) a2r[n] = A2T[n * 128 + d];
    const size_t mbase = (size_t)b * T_ + c * LCH;
    float h[16];
    #pragma unroll
    for (int n = 0; n < 16; ++n) h[n] = 0.f;
    float Dacc = 0.f;
    #pragma unroll 2
    for (int t = 0; t < LCH; ++t) {
        size_t m = mbase + t;
        float dl = xz[m * 256 + d];
        float uv = u[m * 128 + d];
        float du = dl * uv;
        const float* bt = Bm + m * 16;     // wave-uniform row
        Dacc += dl;
        #pragma unroll
        for (int n = 0; n < 16; ++n) {
            float dA = exp2f(dl * a2r[n]);
            h[n] = fmaf(dA, h[n], du * bt[n]);
        }
    }
    const size_t o = ((size_t)(b * CCH + c)) * 16;
    #pragma unroll
    for (int n = 0; n < 16; ++n) Fbuf[(o + n) * 128 + d] = h[n];
    Dbuf[(size_t)(b * CCH + c) * 128 + d] = Dacc;
}

// ---------------- K5b: pass 2 — carry scan over chunks (Hin overwrites Fbuf in place) ---------
__global__ __launch_bounds__(256) void k5b_carry(
    float* Fbuf /* F in, Hin out — aliased read-then-write per element */,
    const float* __restrict__ Dbuf, const float* __restrict__ A2T)
{
    const int tid = blockIdx.x * 256 + threadIdx.x;   // 65536 threads
    const int d = tid & 127, n = (tid >> 7) & 15, b = tid >> 11;
    const float a2 = A2T[n * 128 + d];
    float h = 0.f;
    for (int c = 0; c < CCH; ++c) {
        size_t bc = (size_t)(b * CCH + c);
        size_t i = (bc * 16 + n) * 128 + d;
        float Fv = Fbuf[i];
        float Pv = exp2f(a2 * Dbuf[bc * 128 + d]);
        Fbuf[i] = h;                                  // Hin for chunk c
        h = fmaf(Pv, h, Fv);
    }
}

// ---------------- K5c: pass 3 — full scan with carried h; y overwrites delta in xz ------------
__global__ __launch_bounds__(128) void k5c_scan2(
    float* xzb /* delta in -> y out at [m*256+d]; z half untouched */,
    const float* __restrict__ u, const float* __restrict__ Bm, const float* __restrict__ Cm,
    const float* __restrict__ A2T, const float* __restrict__ Dp, const float* __restrict__ Hin)
{
    const int b = blockIdx.x / CCH, c = blockIdx.x % CCH;
    const int d = threadIdx.x;
    float a2r[16];
    #pragma unroll
    for (int n = 0; n < 16; ++n) a2r[n] = A2T[n * 128 + d];
    const float dpv = Dp[d];
    float h[16];
    const size_t o = ((size_t)(b * CCH + c)) * 16;
    #pragma unroll
    for (int n = 0; n < 16; ++n) h[n] = Hin[(o + n) * 128 + d];
    const size_t mbase = (size_t)b * T_ + c * LCH;
    #pragma unroll 2
    for (int t = 0; t < LCH; ++t) {
        size_t m = mbase + t;
        float dl = xzb[m * 256 + d];
        float uv = u[m * 128 + d];
        float du = dl * uv;
        const float* bt = Bm + m * 16;     // wave-uniform rows
        const float* ct = Cm + m * 16;
        float yacc = uv * dpv;
        #pragma unroll
        for (int n = 0; n < 16; ++n) {
            float dA = exp2f(dl * a2r[n]);
            h[n] = fmaf(dA, h[n], du * bt[n]);
            yacc = fmaf(h[n], ct[n], yacc);
        }
        xzb[m * 256 + d] = yacc;
    }
}

// ---------------- K6: LayerNorm + silu(z) gate + out_proj 128 -> 64 ----------------
__global__ __launch_bounds__(256) void k6_out(
    const float* __restrict__ xz /* y at [m*256+d], z at [m*256+128+d] */,
    const float* __restrict__ lng, const float* __restrict__ lnb,
    const float* __restrict__ Wout, float* __restrict__ y2)
{
    __shared__ float wt[128 * 65];
    __shared__ float yy[4][128];
    const int idx = threadIdx.x;
    for (int f = idx; f < 64 * 128; f += 256) {
        int o = f >> 7, d = f & 127;
        wt[d * 65 + o] = Wout[f];
    }
    const int wid = idx >> 6, lane = idx & 63;
    const int m = blockIdx.x * 4 + wid;
    float2 v = *(const float2*)&xz[(size_t)m * 256 + lane * 2];
    float s = v.x + v.y;
    float sq = v.x * v.x + v.y * v.y;
    #pragma unroll
    for (int off = 32; off; off >>= 1) { s += __shfl_xor(s, off); sq += __shfl_xor(sq, off); }
    float mu = s * (1.f / 128.f);
    float var = sq * (1.f / 128.f) - mu * mu;
    float rstd = rsqrtf(var + 1e-5f);
    float2 g  = *(const float2*)&lng[lane * 2];
    float2 be = *(const float2*)&lnb[lane * 2];
    float2 z  = *(const float2*)&xz[(size_t)m * 256 + 128 + lane * 2];
    float y0 = ((v.x - mu) * rstd * g.x + be.x) * silu_(z.x);
    float y1 = ((v.y - mu) * rstd * g.y + be.y) * silu_(z.y);
    yy[wid][lane * 2] = y0; yy[wid][lane * 2 + 1] = y1;
    __syncthreads();
    float acc = 0.f;
    const float* yrow = yy[wid];
    #pragma unroll 4
    for (int d = 0; d < 128; ++d) acc = fmaf(yrow[d], wt[d * 65 + lane], acc);
    y2[(size_t)m * 64 + lane] = acc;
}

// ---------------- K7: avg-pool(50,15) + classifier ----------------
__global__ __launch_bounds__(256) void k7_cls(
    const float* __restrict__ y2, const float* __restrict__ wcls,
    const float* __restrict__ clsb, float* __restrict__ out)
{
    __shared__ float pl[64 * 65];
    __shared__ float red[4][4];
    const int b = blockIdx.x, idx = threadIdx.x;
    const int o = idx & 63, pg = idx >> 6;
    for (int p = pg; p < 64; p += 4) {
        float s = 0.f;
        int tb = p * 15;
        for (int j = 0; j < 50; ++j) s += y2[(size_t)(b * T_ + tb + j) * 64 + o];
        pl[p * 65 + o] = s * 0.02f;
    }
    __syncthreads();
    float acc[4] = {0.f, 0.f, 0.f, 0.f};
    for (int f = idx; f < 4096; f += 256) {
        int oo = f >> 6, pp = f & 63;
        float v = pl[pp * 65 + oo];
        #pragma unroll
        for (int c = 0; c < 4; ++c) acc[c] = fmaf(wcls[c * 4096 + f], v, acc[c]);
    }
    const int wid = idx >> 6, lane = idx & 63;
    #pragma unroll
    for (int c = 0; c < 4; ++c) {
        float a = acc[c];
        #pragma unroll
        for (int off = 32; off; off >>= 1) a += __shfl_xor(a, off);
        if (lane == 0) red[wid][c] = a;
    }
    __syncthreads();
    if (idx < 4)
        out[b * 4 + idx] = red[0][idx] + red[1][idx] + red[2][idx] + red[3][idx] + clsb[idx];
}

// ---------------- launch ----------------
extern "C" void kernel_launch(void* const* d_in, const int* in_sizes, int n_in,
                              void* d_out, int out_size, void* d_ws, size_t ws_size,
                              hipStream_t stream) {
    if (ws_size < WS_FLOATS * sizeof(float)) return;   // clean failure instead of OOB fault

    const float* x        = (const float*)d_in[0];
    const float* sconv_w  = (const float*)d_in[1];
    const float* bn1_g    = (const float*)d_in[2];
    const float* bn1_b    = (const float*)d_in[3];
    const float* bn1_m    = (const float*)d_in[4];
    const float* bn1_v    = (const float*)d_in[5];
    const float* enc_w    = (const float*)d_in[6];
    const float* enc_b    = (const float*)d_in[7];
    const float* bn2_g    = (const float*)d_in[8];
    const float* bn2_b    = (const float*)d_in[9];
    const float* bn2_m    = (const float*)d_in[10];
    const float* bn2_v    = (const float*)d_in[11];
    const float* in_proj_w= (const float*)d_in[12];
    const float* conv1d_w = (const float*)d_in[13];
    const float* conv1d_b = (const float*)d_in[14];
    const float* x_proj_w = (const float*)d_in[15];
    const float* dt_proj_w= (const float*)d_in[16];
    const float* dt_proj_b= (const float*)d_in[17];
    const float* A_log    = (const float*)d_in[18];
    const float* Dp       = (const float*)d_in[19];
    const float* ln_g     = (const float*)d_in[20];
    const float* ln_b     = (const float*)d_in[21];
    const float* out_proj_w=(const float*)d_in[22];
    const float* cls_w    = (const float*)d_in[23];
    const float* cls_b    = (const float*)d_in[24];

    float* ws = (float*)d_ws;
    float* Mmat  = ws + OFF_M;
    float* bias2 = ws + OFF_B2;
    float* Weff  = ws + OFF_WEFF;
    float* beff  = ws + OFF_BEFF;
    float* A2T   = ws + OFF_A2;
    float* wcls  = ws + OFF_WCLS;
    float* x2    = ws + OFF_X2;     // later reused as y2
    float* xz    = ws + OFF_XZ;     // xs -> delta -> y ; z half
    float* u     = ws + OFF_U;
    float* Fbuf  = ws + OFF_F;      // F then Hin (in place)
    float* Dbuf  = ws + OFF_D;
    float* Bmb   = ws + OFF_BM;
    float* Cmb   = ws + OFF_CM;

    hipLaunchKernelGGL(k0_prep, dim3(1), dim3(256), 0, stream,
        sconv_w, bn1_g, bn1_b, bn1_m, bn1_v, enc_w, enc_b, bn2_g, bn2_b, bn2_m, bn2_v,
        x_proj_w, dt_proj_w, dt_proj_b, A_log, cls_w,
        Mmat, bias2, Weff, beff, A2T, wcls);

    hipLaunchKernelGGL(k1_frontend, dim3(32 * 32), dim3(256), 0, stream, x, Mmat, bias2, x2);
    hipLaunchKernelGGL(k2_inproj, dim3(500 * 4), dim3(256), 0, stream, x2, in_proj_w, xz);
    hipLaunchKernelGGL(k3_conv, dim3(4000), dim3(256), 0, stream, xz, conv1d_w, conv1d_b, u);
    hipLaunchKernelGGL(k4_xproj, dim3(500 * 3), dim3(256), 0, stream, u, Weff, beff, xz, Bmb, Cmb);
    hipLaunchKernelGGL(k5a_scan1, dim3(B_ * CCH), dim3(128), 0, stream, xz, u, Bmb, A2T, Fbuf, Dbuf);
    hipLaunchKernelGGL(k5b_carry, dim3(256), dim3(256), 0, stream, Fbuf, Dbuf, A2T);
    hipLaunchKernelGGL(k5c_scan2, dim3(B_ * CCH), dim3(128), 0, stream, xz, u, Bmb, Cmb, A2T, Dp, Fbuf);
    hipLaunchKernelGGL(k6_out, dim3(8000), dim3(256), 0, stream, xz, ln_g, ln_b, out_proj_w, x2);
    hipLaunchKernelGGL(k7_cls, dim3(32), dim3(256), 0, stream, x2, wcls, cls_b, d_out ? (float*)d_out : nullptr);
}

// Round 15
// 349.437 us; speedup vs baseline: 2.7692x; 1.1306x over previous
//
#include <hip/hip_runtime.h>
#include <math.h>

#define B_ 32
#define T_ 1000
#define M_ 32000   // B_*T_
#define CCH 50     // scan chunks
#define LCH 20     // steps per chunk (CCH*LCH == T_)

// ---------------- workspace layout (float offsets) ----------------
constexpr size_t OFF_M     = 0;                       // 64*44
constexpr size_t OFF_B2    = 2816;                    // 64
constexpr size_t OFF_WEFF  = 2880;                    // 160*128
constexpr size_t OFF_BEFF  = 23360;                   // 160
constexpr size_t OFF_A2    = 23520;                   // 16*128 (transposed: [n][d])
constexpr size_t OFF_WCLS  = 25568;                   // 4*4096
constexpr size_t OFF_X2    = 41952;                   // 32000*64   (also y2 after K6)
constexpr size_t OFF_XZ    = OFF_X2 + 2048000;        // 32000*256: xs->delta->y ; z half
constexpr size_t OFF_U     = OFF_XZ + 8192000;        // 32000*128
constexpr size_t OFF_F     = OFF_U  + 4096000;        // 32*50*16*128 = 3,276,800 (F, then Hin)
constexpr size_t OFF_D     = OFF_F  + 3276800;        // 32*50*128    =   204,800 (sum-delta)
constexpr size_t OFF_BM    = OFF_D  + 204800;         // 32000*16
constexpr size_t OFF_CM    = OFF_BM + 512000;         // 32000*16
constexpr size_t WS_FLOATS = OFF_CM + 512000;         // 18,883,552 floats ≈ 75.5 MB (≤ proven 78)

__device__ __forceinline__ float sigm_(float x)  { return 1.f / (1.f + __expf(-x)); }
__device__ __forceinline__ float silu_(float x)  { return x * sigm_(x); }
__device__ __forceinline__ float softp_(float x) { return fmaxf(x, 0.f) + log1pf(__expf(-fabsf(x))); }

// ---------------- K0: fold all small params (6 parallel blocks, LDS-staged) ----------------
// block 0: Mmat + bias2 (enc_w/sconv_w staged in LDS — was the 85 µs latency chain)
// block 1: Weff + beff + A2T
// blocks 2-5: wcls row (blockIdx-2)
__global__ __launch_bounds__(256) void k0_prep(
    const float* __restrict__ sconv_w, const float* __restrict__ bn1_g, const float* __restrict__ bn1_b,
    const float* __restrict__ bn1_m, const float* __restrict__ bn1_v,
    const float* __restrict__ enc_w, const float* __restrict__ enc_b,
    const float* __restrict__ bn2_g, const float* __restrict__ bn2_b,
    const float* __restrict__ bn2_m, const float* __restrict__ bn2_v,
    const float* __restrict__ xpw, const float* __restrict__ dtw, const float* __restrict__ dtb,
    const float* __restrict__ A_log, const float* __restrict__ cls_w,
    float* __restrict__ Mmat, float* __restrict__ bias2, float* __restrict__ Weff,
    float* __restrict__ beff, float* __restrict__ A2T, float* __restrict__ wcls)
{
    __shared__ float lds[11392];
    const int idx = threadIdx.x;
    const int blk = blockIdx.x;

    if (blk == 0) {
        float* ew  = lds;            // 8192 = 64*64*2
        float* sw  = lds + 8192;     // 2816 = 128*22
        float* s1  = lds + 11008;    // 128
        float* b1  = lds + 11136;    // 128
        float* s2  = lds + 11264;    // 64
        float* b2f = lds + 11328;    // 64
        for (int e = idx; e < 8192; e += 256) ew[e] = enc_w[e];
        for (int e = idx; e < 2816; e += 256) sw[e] = sconv_w[e];
        if (idx < 128) {
            float s = bn1_g[idx] * rsqrtf(bn1_v[idx] + 1e-5f);
            s1[idx] = s; b1[idx] = bn1_b[idx] - bn1_m[idx] * s;
        }
        if (idx < 64) {
            float s = bn2_g[idx] * rsqrtf(bn2_v[idx] + 1e-5f);
            s2[idx] = s; b2f[idx] = bn2_b[idx] - bn2_m[idx] * s;
        }
        __syncthreads();
        // folded frontend matrix M[o][j], j in [0,44): group g=j/22, tap i=j%22
        for (int e = idx; e < 64 * 44; e += 256) {
            int o = e / 44, j = e % 44, g = j / 22, i = j % 22;
            float acc = 0.f;
            for (int cc = 0; cc < 64; ++cc) {
                int c = g * 64 + cc;
                acc += ew[(o * 64 + cc) * 2 + g] * s1[c] * sw[c * 22 + i];
            }
            Mmat[e] = acc * s2[o];
        }
        if (idx < 64) {
            float acc = 0.f;
            for (int c = 0; c < 128; ++c) {
                int g = c >> 6, i = c & 63;
                acc += ew[(idx * 64 + i) * 2 + g] * b1[c];
            }
            bias2[idx] = s2[idx] * (acc + enc_b[idx]) + b2f[idx];
        }
    } else if (blk == 1) {
        float* xp = lds;             // 4608 = 36*128
        float* dw = lds + 4608;      // 512 = 128*4
        for (int e = idx; e < 36 * 128; e += 256) xp[e] = xpw[e];
        for (int e = idx; e < 512; e += 256)      dw[e] = dtw[e];
        __syncthreads();
        // Weff rows 0..127 = dt_proj_w @ x_proj_w[0:4]
        for (int e = idx; e < 128 * 128; e += 256) {
            int d = e >> 7, k = e & 127;
            float acc = 0.f;
            #pragma unroll
            for (int r = 0; r < 4; ++r) acc += dw[d * 4 + r] * xp[r * 128 + k];
            Weff[e] = acc;
        }
        // rows 128..159 = x_proj rows 4..35 (B then C)
        for (int e = idx; e < 32 * 128; e += 256) Weff[128 * 128 + e] = xp[512 + e];
        if (idx < 160) beff[idx] = (idx < 128) ? dtb[idx] : 0.f;
        const float LOG2E = 1.4426950408889634f;
        for (int e = idx; e < 2048; e += 256) {
            int n = e >> 7, d = e & 127;
            A2T[e] = -expf(A_log[d * 16 + n]) * LOG2E;
        }
    } else {
        // normalized classifier weight row c
        const int c = blk - 2;       // 0..3
        float* red = lds;            // 4
        float p = 0.f;
        for (int f = idx; f < 4096; f += 256) { float v = cls_w[c * 4096 + f]; p += v * v; }
        #pragma unroll
        for (int off = 32; off; off >>= 1) p += __shfl_xor(p, off);
        const int wid = idx >> 6, lane = idx & 63;
        if (lane == 0) red[wid] = p;
        __syncthreads();
        float tot = red[0] + red[1] + red[2] + red[3];
        float sc = fminf(1.f, 0.5f / (sqrtf(tot) + 1e-7f));
        for (int f = idx; f < 4096; f += 256) wcls[c * 4096 + f] = cls_w[c * 4096 + f] * sc;
    }
}

// ---------------- K1: folded frontend GEMM 44 -> 64 ----------------
__global__ __launch_bounds__(256) void k1_frontend(
    const float* __restrict__ x, const float* __restrict__ Mmat,
    const float* __restrict__ bias2, float* __restrict__ x2)
{
    __shared__ float Ml[64 * 44];
    __shared__ float xl[44][32];
    const int b = blockIdx.x >> 5, tile = blockIdx.x & 31;
    const int t0 = tile * 32;
    const int idx = threadIdx.x;
    for (int e = idx; e < 64 * 44; e += 256) Ml[e] = Mmat[e];
    {
        int i = idx & 31, j0 = idx >> 5;
        for (int j = j0; j < 44; j += 8) {
            int t = t0 + i;
            xl[j][i] = (t < T_) ? x[(b * 44 + j) * T_ + t] : 0.f;
        }
    }
    __syncthreads();
    const int tl = idx & 31, os = idx >> 5;
    const int t = t0 + tl;
    if (t >= T_) return;
    float acc[8];
    #pragma unroll
    for (int q = 0; q < 8; ++q) acc[q] = bias2[os * 8 + q];
    for (int j = 0; j < 44; ++j) {
        float xv = xl[j][tl];
        #pragma unroll
        for (int q = 0; q < 8; ++q) acc[q] = fmaf(Ml[(os * 8 + q) * 44 + j], xv, acc[q]);
    }
    float4* dst = (float4*)&x2[((size_t)(b * T_ + t)) * 64 + os * 8];
    dst[0] = make_float4(acc[0], acc[1], acc[2], acc[3]);
    dst[1] = make_float4(acc[4], acc[5], acc[6], acc[7]);
}

// ---------------- K2: in_proj GEMM 64 -> 256 ----------------
__global__ __launch_bounds__(256) void k2_inproj(
    const float* __restrict__ x2, const float* __restrict__ W, float* __restrict__ xz)
{
    __shared__ float al[64 * 68];
    __shared__ float bl[64 * 68];
    const int mt = blockIdx.x >> 2, nt = blockIdx.x & 3;
    const int m0 = mt * 64, n0 = nt * 64;
    const int idx = threadIdx.x;
    {
        int mp = idx >> 2, kq = idx & 3;
        #pragma unroll
        for (int f = 0; f < 4; ++f) {
            int k = kq * 16 + f * 4;
            float4 v = *(const float4*)&x2[(size_t)(m0 + mp) * 64 + k];
            al[(k + 0) * 68 + mp] = v.x; al[(k + 1) * 68 + mp] = v.y;
            al[(k + 2) * 68 + mp] = v.z; al[(k + 3) * 68 + mp] = v.w;
            float4 w = *(const float4*)&W[(size_t)(n0 + mp) * 64 + k];
            bl[(k + 0) * 68 + mp] = w.x; bl[(k + 1) * 68 + mp] = w.y;
            bl[(k + 2) * 68 + mp] = w.z; bl[(k + 3) * 68 + mp] = w.w;
        }
    }
    __syncthreads();
    const int ti = idx >> 4, ni = idx & 15;
    float acc[4][4] = {};
    for (int k = 0; k < 64; ++k) {
        float4 a = *(const float4*)&al[k * 68 + ti * 4];
        float4 w = *(const float4*)&bl[k * 68 + ni * 4];
        float av[4] = {a.x, a.y, a.z, a.w};
        float wv[4] = {w.x, w.y, w.z, w.w};
        #pragma unroll
        for (int r = 0; r < 4; ++r)
            #pragma unroll
            for (int c = 0; c < 4; ++c) acc[r][c] = fmaf(av[r], wv[c], acc[r][c]);
    }
    #pragma unroll
    for (int r = 0; r < 4; ++r)
        *(float4*)&xz[(size_t)(m0 + ti * 4 + r) * 256 + n0 + ni * 4] =
            make_float4(acc[r][0], acc[r][1], acc[r][2], acc[r][3]);
}

// ---------------- K3: depthwise conv1d(3) + silu -> u ----------------
__global__ __launch_bounds__(256) void k3_conv(
    const float* __restrict__ xz, const float* __restrict__ cw,
    const float* __restrict__ cb, float* __restrict__ u)
{
    const int gid = blockIdx.x * 256 + threadIdx.x;   // 32000*32
    const int m = gid >> 5, d4 = gid & 31;
    const int t = m % T_;
    const int d0 = d4 * 4;
    float4 z4 = make_float4(0.f, 0.f, 0.f, 0.f);
    float4 vm = (t > 0)      ? *(const float4*)&xz[(size_t)(m - 1) * 256 + d0] : z4;
    float4 v0 =                *(const float4*)&xz[(size_t)(m)     * 256 + d0];
    float4 vp = (t < T_ - 1) ? *(const float4*)&xz[(size_t)(m + 1) * 256 + d0] : z4;
    const float* pm = (const float*)&vm;
    const float* p0 = (const float*)&v0;
    const float* pp = (const float*)&vp;
    float r[4];
    #pragma unroll
    for (int e = 0; e < 4; ++e) {
        int d = d0 + e;
        float a = pm[e] * cw[d * 3 + 0] + p0[e] * cw[d * 3 + 1] + pp[e] * cw[d * 3 + 2] + cb[d];
        r[e] = silu_(a);
    }
    *(float4*)&u[(size_t)m * 128 + d0] = make_float4(r[0], r[1], r[2], r[3]);
}

// ---------------- K4: fused x_proj+dt GEMM 128 -> 160 (softplus -> delta into xz xs-half; B, C) --
__global__ __launch_bounds__(256) void k4_xproj(
    const float* __restrict__ u, const float* __restrict__ Weff, const float* __restrict__ beff,
    float* __restrict__ xz /* delta dest, stride 256 */,
    float* __restrict__ Bm, float* __restrict__ Cm)
{
    __shared__ float al[64 * 68];
    __shared__ float bl[64 * 68];
    const int mt = blockIdx.x / 3, nt = blockIdx.x % 3;
    const int m0 = mt * 64, n0 = nt * 64;
    const int idx = threadIdx.x;
    const int ti = idx >> 4, ni = idx & 15;
    float acc[4][4] = {};
    for (int kb = 0; kb < 128; kb += 64) {
        __syncthreads();
        {
            int mp = idx >> 2, kq = idx & 3;
            #pragma unroll
            for (int f = 0; f < 4; ++f) {
                int k = kq * 16 + f * 4;
                float4 v = *(const float4*)&u[(size_t)(m0 + mp) * 128 + kb + k];
                al[(k + 0) * 68 + mp] = v.x; al[(k + 1) * 68 + mp] = v.y;
                al[(k + 2) * 68 + mp] = v.z; al[(k + 3) * 68 + mp] = v.w;
                int row = n0 + mp;
                float4 w = (row < 160) ? *(const float4*)&Weff[(size_t)row * 128 + kb + k]
                                       : make_float4(0.f, 0.f, 0.f, 0.f);
                bl[(k + 0) * 68 + mp] = w.x; bl[(k + 1) * 68 + mp] = w.y;
                bl[(k + 2) * 68 + mp] = w.z; bl[(k + 3) * 68 + mp] = w.w;
            }
        }
        __syncthreads();
        for (int k = 0; k < 64; ++k) {
            float4 a = *(const float4*)&al[k * 68 + ti * 4];
            float4 w = *(const float4*)&bl[k * 68 + ni * 4];
            float av[4] = {a.x, a.y, a.z, a.w};
            float wv[4] = {w.x, w.y, w.z, w.w};
            #pragma unroll
            for (int r = 0; r < 4; ++r)
                #pragma unroll
                for (int c = 0; c < 4; ++c) acc[r][c] = fmaf(av[r], wv[c], acc[r][c]);
        }
    }
    if (nt < 2) {
        #pragma unroll
        for (int r = 0; r < 4; ++r) {
            int m = m0 + ti * 4 + r;
            float dl[4];
            #pragma unroll
            for (int c = 0; c < 4; ++c) {
                int n = n0 + ni * 4 + c;
                dl[c] = softp_(acc[r][c] + beff[n]);
            }
            *(float4*)&xz[(size_t)m * 256 + n0 + ni * 4] = make_float4(dl[0], dl[1], dl[2], dl[3]);
        }
    } else if (ni < 8) {
        float* dst = (ni < 4) ? Bm : Cm;
        int q0 = (ni & 3) * 4;
        #pragma unroll
        for (int r = 0; r < 4; ++r) {
            int m = m0 + ti * 4 + r;
            #pragma unroll
            for (int c = 0; c < 4; ++c) dst[(size_t)m * 16 + q0 + c] = acc[r][c];
        }
    }
}

// ---------------- K5a: pass 1 — per-chunk local final state F and sum-delta D ----------------
// lane owns one d; 16 states in registers; B row via wave-uniform (scalar) loads
__global__ __launch_bounds__(128) void k5a_scan1(
    const float* __restrict__ xz /* delta at [m*256+d] */, const float* __restrict__ u,
    const float* __restrict__ Bm, const float* __restrict__ A2T,
    float* __restrict__ Fbuf, float* __restrict__ Dbuf)
{
    const int b = blockIdx.x / CCH, c = blockIdx.x % CCH;
    const int d = threadIdx.x;
    float a2r[16];
    #pragma unroll
    for (int n = 0; n < 16; ++n) a2r[n] = A2T[n * 128 + d];
    const size_t mbase = (size_t)b * T_ + c * LCH;
    float h[16];
    #pragma unroll
    for (int n = 0; n < 16; ++n) h[n] = 0.f;
    float Dacc = 0.f;
    #pragma unroll 2
    for (int t = 0; t < LCH; ++t) {
        size_t m = mbase + t;
        float dl = xz[m * 256 + d];
        float uv = u[m * 128 + d];
        float du = dl * uv;
        const float* bt = Bm + m * 16;     // wave-uniform row
        Dacc += dl;
        #pragma unroll
        for (int n = 0; n < 16; ++n) {
            float dA = exp2f(dl * a2r[n]);
            h[n] = fmaf(dA, h[n], du * bt[n]);
        }
    }
    const size_t o = ((size_t)(b * CCH + c)) * 16;
    #pragma unroll
    for (int n = 0; n < 16; ++n) Fbuf[(o + n) * 128 + d] = h[n];
    Dbuf[(size_t)(b * CCH + c) * 128 + d] = Dacc;
}

// ---------------- K5b: pass 2 — carry scan over chunks (Hin overwrites Fbuf in place) ---------
__global__ __launch_bounds__(256) void k5b_carry(
    float* Fbuf /* F in, Hin out — aliased read-then-write per element */,
    const float* __restrict__ Dbuf, const float* __restrict__ A2T)
{
    const int tid = blockIdx.x * 256 + threadIdx.x;   // 65536 threads
    const int d = tid & 127, n = (tid >> 7) & 15, b = tid >> 11;
    const float a2 = A2T[n * 128 + d];
    float h = 0.f;
    for (int c = 0; c < CCH; ++c) {
        size_t bc = (size_t)(b * CCH + c);
        size_t i = (bc * 16 + n) * 128 + d;
        float Fv = Fbuf[i];
        float Pv = exp2f(a2 * Dbuf[bc * 128 + d]);
        Fbuf[i] = h;                                  // Hin for chunk c
        h = fmaf(Pv, h, Fv);
    }
}

// ---------------- K5c: pass 3 — full scan with carried h; y overwrites delta in xz ------------
__global__ __launch_bounds__(128) void k5c_scan2(
    float* xzb /* delta in -> y out at [m*256+d]; z half untouched */,
    const float* __restrict__ u, const float* __restrict__ Bm, const float* __restrict__ Cm,
    const float* __restrict__ A2T, const float* __restrict__ Dp, const float* __restrict__ Hin)
{
    const int b = blockIdx.x / CCH, c = blockIdx.x % CCH;
    const int d = threadIdx.x;
    float a2r[16];
    #pragma unroll
    for (int n = 0; n < 16; ++n) a2r[n] = A2T[n * 128 + d];
    const float dpv = Dp[d];
    float h[16];
    const size_t o = ((size_t)(b * CCH + c)) * 16;
    #pragma unroll
    for (int n = 0; n < 16; ++n) h[n] = Hin[(o + n) * 128 + d];
    const size_t mbase = (size_t)b * T_ + c * LCH;
    #pragma unroll 2
    for (int t = 0; t < LCH; ++t) {
        size_t m = mbase + t;
        float dl = xzb[m * 256 + d];
        float uv = u[m * 128 + d];
        float du = dl * uv;
        const float* bt = Bm + m * 16;     // wave-uniform rows
        const float* ct = Cm + m * 16;
        float yacc = uv * dpv;
        #pragma unroll
        for (int n = 0; n < 16; ++n) {
            float dA = exp2f(dl * a2r[n]);
            h[n] = fmaf(dA, h[n], du * bt[n]);
            yacc = fmaf(h[n], ct[n], yacc);
        }
        xzb[m * 256 + d] = yacc;
    }
}

// ---------------- K6: LayerNorm + silu(z) gate + out_proj 128 -> 64 ----------------
__global__ __launch_bounds__(256) void k6_out(
    const float* __restrict__ xz /* y at [m*256+d], z at [m*256+128+d] */,
    const float* __restrict__ lng, const float* __restrict__ lnb,
    const float* __restrict__ Wout, float* __restrict__ y2)
{
    __shared__ float wt[128 * 65];
    __shared__ float yy[4][128];
    const int idx = threadIdx.x;
    for (int f = idx; f < 64 * 128; f += 256) {
        int o = f >> 7, d = f & 127;
        wt[d * 65 + o] = Wout[f];
    }
    const int wid = idx >> 6, lane = idx & 63;
    const int m = blockIdx.x * 4 + wid;
    float2 v = *(const float2*)&xz[(size_t)m * 256 + lane * 2];
    float s = v.x + v.y;
    float sq = v.x * v.x + v.y * v.y;
    #pragma unroll
    for (int off = 32; off; off >>= 1) { s += __shfl_xor(s, off); sq += __shfl_xor(sq, off); }
    float mu = s * (1.f / 128.f);
    float var = sq * (1.f / 128.f) - mu * mu;
    float rstd = rsqrtf(var + 1e-5f);
    float2 g  = *(const float2*)&lng[lane * 2];
    float2 be = *(const float2*)&lnb[lane * 2];
    float2 z  = *(const float2*)&xz[(size_t)m * 256 + 128 + lane * 2];
    float y0 = ((v.x - mu) * rstd * g.x + be.x) * silu_(z.x);
    float y1 = ((v.y - mu) * rstd * g.y + be.y) * silu_(z.y);
    yy[wid][lane * 2] = y0; yy[wid][lane * 2 + 1] = y1;
    __syncthreads();
    float acc = 0.f;
    const float* yrow = yy[wid];
    #pragma unroll 4
    for (int d = 0; d < 128; ++d) acc = fmaf(yrow[d], wt[d * 65 + lane], acc);
    y2[(size_t)m * 64 + lane] = acc;
}

// ---------------- K7: avg-pool(50,15) + classifier ----------------
__global__ __launch_bounds__(256) void k7_cls(
    const float* __restrict__ y2, const float* __restrict__ wcls,
    const float* __restrict__ clsb, float* __restrict__ out)
{
    __shared__ float pl[64 * 65];
    __shared__ float red[4][4];
    const int b = blockIdx.x, idx = threadIdx.x;
    const int o = idx & 63, pg = idx >> 6;
    for (int p = pg; p < 64; p += 4) {
        float s = 0.f;
        int tb = p * 15;
        for (int j = 0; j < 50; ++j) s += y2[(size_t)(b * T_ + tb + j) * 64 + o];
        pl[p * 65 + o] = s * 0.02f;
    }
    __syncthreads();
    float acc[4] = {0.f, 0.f, 0.f, 0.f};
    for (int f = idx; f < 4096; f += 256) {
        int oo = f >> 6, pp = f & 63;
        float v = pl[pp * 65 + oo];
        #pragma unroll
        for (int c = 0; c < 4; ++c) acc[c] = fmaf(wcls[c * 4096 + f], v, acc[c]);
    }
    const int wid = idx >> 6, lane = idx & 63;
    #pragma unroll
    for (int c = 0; c < 4; ++c) {
        float a = acc[c];
        #pragma unroll
        for (int off = 32; off; off >>= 1) a += __shfl_xor(a, off);
        if (lane == 0) red[wid][c] = a;
    }
    __syncthreads();
    if (idx < 4)
        out[b * 4 + idx] = red[0][idx] + red[1][idx] + red[2][idx] + red[3][idx] + clsb[idx];
}

// ---------------- launch ----------------
extern "C" void kernel_launch(void* const* d_in, const int* in_sizes, int n_in,
                              void* d_out, int out_size, void* d_ws, size_t ws_size,
                              hipStream_t stream) {
    if (ws_size < WS_FLOATS * sizeof(float)) return;   // clean failure instead of OOB fault

    const float* x        = (const float*)d_in[0];
    const float* sconv_w  = (const float*)d_in[1];
    const float* bn1_g    = (const float*)d_in[2];
    const float* bn1_b    = (const float*)d_in[3];
    const float* bn1_m    = (const float*)d_in[4];
    const float* bn1_v    = (const float*)d_in[5];
    const float* enc_w    = (const float*)d_in[6];
    const float* enc_b    = (const float*)d_in[7];
    const float* bn2_g    = (const float*)d_in[8];
    const float* bn2_b    = (const float*)d_in[9];
    const float* bn2_m    = (const float*)d_in[10];
    const float* bn2_v    = (const float*)d_in[11];
    const float* in_proj_w= (const float*)d_in[12];
    const float* conv1d_w = (const float*)d_in[13];
    const float* conv1d_b = (const float*)d_in[14];
    const float* x_proj_w = (const float*)d_in[15];
    const float* dt_proj_w= (const float*)d_in[16];
    const float* dt_proj_b= (const float*)d_in[17];
    const float* A_log    = (const float*)d_in[18];
    const float* Dp       = (const float*)d_in[19];
    const float* ln_g     = (const float*)d_in[20];
    const float* ln_b     = (const float*)d_in[21];
    const float* out_proj_w=(const float*)d_in[22];
    const float* cls_w    = (const float*)d_in[23];
    const float* cls_b    = (const float*)d_in[24];

    float* ws = (float*)d_ws;
    float* Mmat  = ws + OFF_M;
    float* bias2 = ws + OFF_B2;
    float* Weff  = ws + OFF_WEFF;
    float* beff  = ws + OFF_BEFF;
    float* A2T   = ws + OFF_A2;
    float* wcls  = ws + OFF_WCLS;
    float* x2    = ws + OFF_X2;     // later reused as y2
    float* xz    = ws + OFF_XZ;     // xs -> delta -> y ; z half
    float* u     = ws + OFF_U;
    float* Fbuf  = ws + OFF_F;      // F then Hin (in place)
    float* Dbuf  = ws + OFF_D;
    float* Bmb   = ws + OFF_BM;
    float* Cmb   = ws + OFF_CM;

    hipLaunchKernelGGL(k0_prep, dim3(6), dim3(256), 0, stream,
        sconv_w, bn1_g, bn1_b, bn1_m, bn1_v, enc_w, enc_b, bn2_g, bn2_b, bn2_m, bn2_v,
        x_proj_w, dt_proj_w, dt_proj_b, A_log, cls_w,
        Mmat, bias2, Weff, beff, A2T, wcls);

    hipLaunchKernelGGL(k1_frontend, dim3(32 * 32), dim3(256), 0, stream, x, Mmat, bias2, x2);
    hipLaunchKernelGGL(k2_inproj, dim3(500 * 4), dim3(256), 0, stream, x2, in_proj_w, xz);
    hipLaunchKernelGGL(k3_conv, dim3(4000), dim3(256), 0, stream, xz, conv1d_w, conv1d_b, u);
    hipLaunchKernelGGL(k4_xproj, dim3(500 * 3), dim3(256), 0, stream, u, Weff, beff, xz, Bmb, Cmb);
    hipLaunchKernelGGL(k5a_scan1, dim3(B_ * CCH), dim3(128), 0, stream, xz, u, Bmb, A2T, Fbuf, Dbuf);
    hipLaunchKernelGGL(k5b_carry, dim3(256), dim3(256), 0, stream, Fbuf, Dbuf, A2T);
    hipLaunchKernelGGL(k5c_scan2, dim3(B_ * CCH), dim3(128), 0, stream, xz, u, Bmb, Cmb, A2T, Dp, Fbuf);
    hipLaunchKernelGGL(k6_out, dim3(8000), dim3(256), 0, stream, xz, ln_g, ln_b, out_proj_w, x2);
    hipLaunchKernelGGL(k7_cls, dim3(32), dim3(256), 0, stream, x2, wcls, cls_b, d_out ? (float*)d_out : nullptr);
}